// Round 5
// baseline (411.962 us; speedup 1.0000x reference)
//
#include <hip/hip_runtime.h>

typedef unsigned short u16;
typedef unsigned int u32;
typedef unsigned long long u64;
typedef __attribute__((ext_vector_type(8))) short short8;
typedef __attribute__((ext_vector_type(4))) float f32x4;

#define N_ELEM 8388608
#define NH 32
#define SEQ 2048
#define HD 128
#define KTOP 32768u
#define CAND_CAP 8192u

__device__ __forceinline__ u16 f2bf(float f) {
  union { float f; u32 u; } v; v.f = f;
  u32 r = v.u + 0x7fffu + ((v.u >> 16) & 1u);
  return (u16)(r >> 16);
}

// fp32 quant-dequant, exact reference semantics; keeps outliers & sinks verbatim
__device__ __forceinline__ float dqf(float x, u32 t, u64 Kr, u32 idx, bool sink, float scale) {
  union { float f; u32 u; } w; w.f = x;
  const u32 ab = w.u & 0x7fffffffu;
  const u32 bin = ab >> 16;
  const bool keep = sink || (bin > t) ||
                    (bin == t && ((((u64)ab) << 32) | (u32)(~idx)) >= Kr);
  if (keep) return x;
  float q = rintf(x / scale);            // round-half-even == jnp.round
  q = fminf(fmaxf(q, -8.0f), 7.0f);
  return q * scale;
}

// packed fp32->bf16 RNE (identical rounding to f2bf); no builtin on gfx950
__device__ __forceinline__ u32 cvtpk_bf16(float lo, float hi) {
  u32 r;
  asm("v_cvt_pk_bf16_f32 %0, %1, %2" : "=v"(r) : "v"(lo), "v"(hi));
  return r;
}

__device__ __forceinline__ float bperm_f(int ibyte, float x) {
  union { float f; int i; } a, b;
  a.f = x;
  b.i = __builtin_amdgcn_ds_bpermute(ibyte, a.i);
  return b.f;
}

// ---------------- K1: 32768-bin histogram of fp32 abs-bits>>16 ----------------
__global__ __launch_bounds__(256) void hist_kernel(const float* __restrict__ k,
                                                   const float* __restrict__ v,
                                                   u32* __restrict__ histK,
                                                   u32* __restrict__ histV) {
  __shared__ u32 sh[16384];
  const int tensor = blockIdx.x >> 7;
  const int bid = blockIdx.x & 127;
  const float* src = tensor ? v : k;
  u32* gh = tensor ? histV : histK;
  for (int i = threadIdx.x; i < 16384; i += 256) sh[i] = 0;
  __syncthreads();
  const int per = N_ELEM / 128;  // 65536
  const int base = bid * per;
  for (int i = threadIdx.x; i < per / 4; i += 256) {
    f32x4 x = *(const f32x4*)(src + base + i * 4);
#pragma unroll
    for (int j = 0; j < 4; ++j) {
      union { float f; u32 u; } w; w.f = x[j];
      u32 b = (w.u & 0x7fffffffu) >> 16;
      atomicAdd(&sh[b >> 1], 1u << ((b & 1u) * 16));
    }
  }
  __syncthreads();
  for (int i = threadIdx.x; i < 16384; i += 256) {
    u32 w = sh[i];
    u32 lo = w & 0xffffu, hi = w >> 16;
    if (lo) atomicAdd(&gh[2 * i], lo);
    if (hi) atomicAdd(&gh[2 * i + 1], hi);
  }
}

// ---------------- K2: threshold bin t + tie budget r (LDS-cached scans) -------------
__global__ __launch_bounds__(256) void thresh_kernel(const u32* __restrict__ histK,
                                                     const u32* __restrict__ histV,
                                                     u32* __restrict__ ctrl) {
  const u32* hist = blockIdx.x ? histV : histK;
  u32* c = ctrl + blockIdx.x * 8;
  __shared__ u32 part[256];
  __shared__ u32 bins[128];
  __shared__ u32 sh_chunk, sh_cum;
  u32 s = 0;
  for (int i = 0; i < 128; ++i) s += hist[threadIdx.x * 128 + i];
  part[threadIdx.x] = s;
  __syncthreads();
  if (threadIdx.x == 0) {
    u32 cum = 0;
    int chunk = 255;
    while (chunk > 0 && cum + part[chunk] < KTOP) { cum += part[chunk]; --chunk; }
    sh_chunk = (u32)chunk; sh_cum = cum;
  }
  __syncthreads();
  const u32 chunk = sh_chunk;
  if (threadIdx.x < 128) bins[threadIdx.x] = hist[chunk * 128 + threadIdx.x];
  __syncthreads();
  if (threadIdx.x == 0) {
    u32 cum = sh_cum;
    int b = 127;
    while (b > 0 && cum + bins[b] < KTOP) { cum += bins[b]; --b; }
    c[0] = chunk * 128 + (u32)b;
    c[1] = KTOP - cum;
  }
}

// ---------------- K3: fused candidate gather + per-(h,d) max over bin<t -------------
// grid (256, 2): head h = bx>>3, row-eighth = bx&7 (256 rows/block) -> 2 blocks/CU.
__global__ __launch_bounds__(256) void candmax_kernel(const float* __restrict__ k,
                                                      const float* __restrict__ v,
                                                      u32* __restrict__ ctrl,
                                                      u32* __restrict__ caK, u32* __restrict__ ciK,
                                                      u32* __restrict__ caV, u32* __restrict__ ciV,
                                                      u32* __restrict__ kmax,
                                                      u32* __restrict__ vmax) {
  __shared__ u32 colmax[128];
  const int tensor = blockIdx.y;
  const float* src = tensor ? v : k;
  u32* ca = tensor ? caV : caK;
  u32* ci = tensor ? ciV : ciK;
  u32* cnt = &ctrl[tensor * 8 + 4];
  u32* mbuf = tensor ? vmax : kmax;
  const u32 t = ctrl[tensor * 8 + 0];
  const int h = blockIdx.x >> 3;
  const int q8 = blockIdx.x & 7;
  const int tid = threadIdx.x;
  if (tid < 128) colmax[tid] = 0;
  __syncthreads();
  const int c0 = 4 * (tid & 31);
  u32 mx[4] = {0, 0, 0, 0};
  for (int p = 0; p < 32; ++p) {
    const int s = q8 * 256 + p * 8 + (tid >> 5);
    const u32 idx = ((u32)(h * SEQ + s) << 7) + (u32)c0;
    f32x4 x = *(const f32x4*)(src + idx);
    const bool skipmax = (tensor == 1 && s < 4);
#pragma unroll
    for (int j = 0; j < 4; ++j) {
      union { float f; u32 u; } w; w.f = x[j];
      const u32 ab = w.u & 0x7fffffffu;
      const u32 bin = ab >> 16;
      if (bin == t) {
        u32 slot = atomicAdd(cnt, 1u);
        if (slot < CAND_CAP) { ca[slot] = ab; ci[slot] = idx + j; }
      }
      if (bin < t && !skipmax && ab > mx[j]) mx[j] = ab;
    }
  }
#pragma unroll
  for (int j = 0; j < 4; ++j) atomicMax(&colmax[c0 + j], mx[j]);
  __syncthreads();
  if (tid < 128) atomicMax(&mbuf[h * HD + tid], colmax[tid]);
}

// ---------------- K4: Kr = r-th largest key among candidates (LDS-cached) -----------
__global__ __launch_bounds__(256) void ksel_kernel(u32* __restrict__ ctrl,
                                                   const u32* __restrict__ caK, const u32* __restrict__ ciK,
                                                   const u32* __restrict__ caV, const u32* __restrict__ ciV) {
  __shared__ u64 keys[CAND_CAP];
  const int tensor = blockIdx.y;
  u32* c = ctrl + tensor * 8;
  const u32 r = c[1];
  u32 T = c[4];
  if (T > CAND_CAP) T = CAND_CAP;
  const u32* ca = tensor ? caV : caK;
  const u32* ci = tensor ? ciV : ciK;
  for (u32 j = threadIdx.x; j < T; j += 256)
    keys[j] = (((u64)ca[j]) << 32) | (u32)(~ci[j]);
  __syncthreads();
  for (u32 i = blockIdx.x * 256 + threadIdx.x; i < T; i += 32 * 256) {
    const u64 ki = keys[i];
    u32 cnt = 0;
    for (u32 j = 0; j < T; ++j) cnt += (keys[j] > ki) ? 1u : 0u;
    if (cnt == r - 1) { c[2] = (u32)(ki >> 32); c[3] = (u32)ki; }
  }
}

// ---------------- K5: maxfix (fold bin==t non-outliers) + scale, fused --------------
__global__ __launch_bounds__(256) void maxfix_scale_kernel(const u32* __restrict__ ctrl,
                                                           const u32* __restrict__ caK, const u32* __restrict__ ciK,
                                                           const u32* __restrict__ caV, const u32* __restrict__ ciV,
                                                           u32* __restrict__ kmax, u32* __restrict__ vmax,
                                                           float* __restrict__ kscale, float* __restrict__ vscale) {
  const int tensor = blockIdx.x;
  const u32* c = ctrl + tensor * 8;
  const u64 Kr = (((u64)c[2]) << 32) | c[3];
  u32 T = c[4];
  if (T > CAND_CAP) T = CAND_CAP;
  const u32* ca = tensor ? caV : caK;
  const u32* ci = tensor ? ciV : ciK;
  u32* mbuf = tensor ? vmax : kmax;
  for (u32 i = threadIdx.x; i < T; i += 256) {
    const u32 ab = ca[i], idx = ci[i];
    const u64 key = (((u64)ab) << 32) | (u32)(~idx);
    if (key >= Kr) continue;                              // outlier -> excluded
    if (tensor == 1 && ((idx >> 7) & 2047) < 4) continue; // V sink -> excluded
    atomicMax(&mbuf[(idx >> 18) * HD + (idx & 127)], ab);
  }
  __syncthreads();
  float* sbuf = tensor ? vscale : kscale;
  for (int i = threadIdx.x; i < NH * HD; i += 256) {
    union { u32 u; float f; } a; a.u = mbuf[i];
    sbuf[i] = fmaxf(a.f, 1e-6f) / 7.0f;
  }
}

// ---------------- K6: reconstruct K -> krec (row-major) AND V -> vrecT, one launch ---
// blocks [0,2048): K path (grid-stride). blocks [2048,3072): V transpose path.
__global__ __launch_bounds__(256) void recon_kv_kernel(const float* __restrict__ K,
                                                       const float* __restrict__ V,
                                                       const u32* __restrict__ ctrl,
                                                       const float* __restrict__ kscale,
                                                       const float* __restrict__ vscale,
                                                       u16* __restrict__ krec,
                                                       u16* __restrict__ vrecT) {
  __shared__ u32 ld[64][65];   // [d-pair][s_local], pad 64->65 (V path only)
  const int tid = threadIdx.x;
  if (blockIdx.x < 2048) {
    const u32 t = ctrl[0];
    const u64 Kr = (((u64)ctrl[2]) << 32) | ctrl[3];
    const int stride = 2048 * 256;
    for (int i = blockIdx.x * 256 + tid; i < N_ELEM / 4; i += stride) {
      const u32 e = (u32)i * 4;
      const u32 d0 = e & 127, h = e >> 18;
      f32x4 x = *(const f32x4*)(K + e);
      f32x4 sc = *(const f32x4*)(kscale + h * HD + d0);
      u16 y[4];
#pragma unroll
      for (int j = 0; j < 4; ++j) y[j] = f2bf(dqf(x[j], t, Kr, e + j, false, sc[j]));
      *(u32*)(krec + e) = ((u32)y[0]) | (((u32)y[1]) << 16);
      *(u32*)(krec + e + 2) = ((u32)y[2]) | (((u32)y[3]) << 16);
    }
  } else {
    const int b = blockIdx.x - 2048;
    const u32 t = ctrl[8];
    const u64 Kr = (((u64)ctrl[10]) << 32) | ctrl[11];
    const int h = b >> 5, sb = b & 31;
    const int d0 = 4 * (tid & 31);
    f32x4 sc = *(const f32x4*)(vscale + h * HD + d0);
#pragma unroll
    for (int p = 0; p < 8; ++p) {
      const int sl = p * 8 + (tid >> 5);
      const int tok = sb * 64 + sl;
      const bool sink = tok < 4;
      const u32 idx = ((u32)(h * SEQ + tok) << 7) + (u32)d0;
      f32x4 x = *(const f32x4*)(V + idx);
      u16 y[4];
#pragma unroll
      for (int j = 0; j < 4; ++j) y[j] = f2bf(dqf(x[j], t, Kr, idx + j, sink, sc[j]));
      ld[(d0 >> 1)][sl] = ((u32)y[0]) | (((u32)y[1]) << 16);
      ld[(d0 >> 1) + 1][sl] = ((u32)y[2]) | (((u32)y[3]) << 16);
    }
    __syncthreads();
    const int d = tid >> 1, so = (tid & 1) * 32, e = d & 1;
    u16* outp = vrecT + (size_t)(h * 32 + sb) * 8192 + d * 64 + so;
#pragma unroll
    for (int i = 0; i < 4; ++i) {
      short8 y;
#pragma unroll
      for (int m = 0; m < 8; ++m) {
        const u32 w2 = ld[d >> 1][so + i * 8 + m];
        y[m] = (short)(u16)(w2 >> (16 * e));
      }
      *(short8*)(outp + i * 8) = y;
    }
  }
}

// ---------------- K8: flash attention, swapped-QK, K-dbuf + V-direct-from-L2 --------
// Block = head h x pair a: q-tiles {a, 31-a}; 512 threads: waves 0-3 own subtile A,
// waves 4-7 own subtile B; 2 blocks/CU = 16 waves/CU.
// QK^T as mfma(K, Q): lane owns ONE q-row (l16); bit-shuffled K rows make the lane's
// 16 scores exactly the PV A-fragment after v_cvt_pk_bf16_f32 (no P LDS round-trip).
// K tile double-buffered in LDS -> ONE barrier per k-tile; stage overlaps compute.
// V fragments load DIRECTLY from global vrecT (per-lane fixed addresses; L2-resident
// via XCD swizzle: 4 heads/XCD = 4 MB KV = L2) -> no vt buffer, no V LDS traffic,
// PV depends on vmcnt loads issued ~400cyc early instead of barrier-fresh ds_reads.
// T13 defer-max: skip O-rescale while tile max grows < 8 (exp2 domain, P <= 256).
#define SC_QK 0.12751743f   // log2(e)/sqrt(128): exp2-domain softmax
#define NEGS -30000.0f

__global__ __launch_bounds__(512, 4) void flash_pre(const float* __restrict__ Q,
                                                    const u16* __restrict__ krec,
                                                    const u16* __restrict__ vrecT,
                                                    float* __restrict__ Out) {
  __shared__ u16 ks[2][64][132];  // K tile x2 (permuted token rows x channel)

  // XCD swizzle: xcd = b&7 serves heads {xcd, xcd+8, xcd+16, xcd+24}
  const int b = blockIdx.x;       // 512 = 32 heads x 16 pairs
  const int h = (b & 7) + 8 * ((b >> 3) >> 4);
  const int pa = (b >> 3) & 15;
  const int RA = pa << 6;          // q-tile A row base (0..960)
  const int RB = (31 - pa) << 6;   // q-tile B row base (1024..1984)
  const int tid = threadIdx.x;
  const int w = tid >> 6, lane = tid & 63;
  const int ww = w & 3;            // wave index within subtile group
  const int R = (w >> 2) ? RB : RA;  // this wave's subtile row base
  const int l16 = lane & 15, quad = lane >> 4;
  const int qrow16 = ww * 16 + l16;  // this lane's q-row within the 64-row subtile

  int idxR[4];                     // bpermute byte-idx: same-quad lane with l16 = quad*4+r
#pragma unroll
  for (int r = 0; r < 4; ++r) idxR[r] = ((lane & 48) | (quad * 4 + r)) << 2;

  // Q fragment for this wave's subtile (B-operand: col = q = l16)
  short8 qf[4];
  {
    const float* qp = Q + ((size_t)(h * SEQ + R + ww * 16 + l16)) * HD + quad * 8;
#pragma unroll
    for (int c = 0; c < 4; ++c) {
      f32x4 a = *(const f32x4*)(qp + c * 32);
      f32x4 bb = *(const f32x4*)(qp + c * 32 + 4);
      union { u32 u[4]; short8 v; } t;
      t.u[0] = cvtpk_bf16(a[0], a[1]);
      t.u[1] = cvtpk_bf16(a[2], a[3]);
      t.u[2] = cvtpk_bf16(bb[0], bb[1]);
      t.u[3] = cvtpk_bf16(bb[2], bb[3]);
      qf[c] = t.v;
    }
  }

  f32x4 o[8];
#pragma unroll
  for (int i = 0; i < 8; ++i) o[i] = (f32x4){0.f, 0.f, 0.f, 0.f};
  float mrow = NEGS, lrow = 0.f;

  // K staging mapping (512 threads; 64 rows x 256B, 8 thr/row) + prefetch regs
  const int krow = tid >> 3, kqo = (tid & 7) * 16;
  // token->LDS-row bit shuffle: x = [t5 t2 | t4 t3 | t1 t0]
  const int krp = (krow & 35) | (((krow >> 2) & 1) << 4) |
                  (((krow >> 4) & 1) << 3) | (((krow >> 3) & 1) << 2);
  const u16* kbase = krec + ((size_t)h * SEQ + krow) * HD + kqo;
  // V fragment per-lane global base: elem = vbase + kt*8192 + ds*1024 + kc*32
  const u16* vfb = vrecT + (size_t)h * 32 * 8192 + (size_t)l16 * 64 + quad * 8;

  const int ktiles = (RB >> 6) + 1;   // 17..32

  // prologue: stage tile 0 into buf 0, prefetch tile 1
  short8 kr[2];
  kr[0] = *(const short8*)(kbase);
  kr[1] = *(const short8*)(kbase + 8);
  *(short8*)(&ks[0][krp][kqo]) = kr[0];
  *(short8*)(&ks[0][krp][kqo + 8]) = kr[1];
  if (1 < ktiles) {
    const u16* kp = kbase + (size_t)64 * HD;
    kr[0] = *(const short8*)(kp);
    kr[1] = *(const short8*)(kp + 8);
  }
  __syncthreads();

  int cur = 0;
  for (int kt = 0; kt < ktiles; ++kt) {
    const int kb = kt << 6;
    // stage kt+1 into the other buffer (no barrier needed before: that buffer's
    // readers finished before the previous barrier)
    if (kt + 1 < ktiles) {
      *(short8*)(&ks[cur ^ 1][krp][kqo]) = kr[0];
      *(short8*)(&ks[cur ^ 1][krp][kqo + 8]) = kr[1];
    }
    if (kt + 2 < ktiles) {
      const u16* kp = kbase + (size_t)(kt + 2) * 64 * HD;
      kr[0] = *(const short8*)(kp);
      kr[1] = *(const short8*)(kp + 8);
    }
    if (kb <= R) {
      // V frags kc=0: direct global loads (L2-hit), latency hidden under QK+softmax
      const u16* vp = vfb + (size_t)kt * 8192;
      short8 vf[8];
#pragma unroll
      for (int ds = 0; ds < 8; ++ds) vf[ds] = *(const short8*)(vp + ds * 1024);

      // S^T = K Q^T: A = K frags from LDS buf[cur], B = Q regs
      f32x4 s[4];
      __builtin_amdgcn_s_setprio(1);
#pragma unroll
      for (int ni = 0; ni < 4; ++ni) {
        f32x4 acc = (f32x4){0.f, 0.f, 0.f, 0.f};
#pragma unroll
        for (int c = 0; c < 4; ++c) {
          short8 kf = *(const short8*)(&ks[cur][ni * 16 + l16][c * 32 + quad * 8]);
          acc = __builtin_amdgcn_mfma_f32_16x16x32_bf16(kf, qf[c], acc, 0, 0, 0);
        }
        s[ni] = acc;
      }
      __builtin_amdgcn_s_setprio(0);

      // softmax (defer-max); token of s[ni][r] = (ni>>1)*32 + quad*8 + (ni&1)*4 + r
      const bool diag = (kb == R);
#pragma unroll
      for (int ni = 0; ni < 4; ++ni)
#pragma unroll
        for (int r = 0; r < 4; ++r) {
          float sv = s[ni][r] * SC_QK;
          const int tokl = ((ni >> 1) << 5) | (quad << 3) | ((ni & 1) << 2) | r;
          if (diag && tokl > qrow16) sv = NEGS;
          s[ni][r] = sv;
        }
      float m01 = fmaxf(fmaxf(fmaxf(s[0][0], s[0][1]), fmaxf(s[0][2], s[0][3])),
                        fmaxf(fmaxf(s[1][0], s[1][1]), fmaxf(s[1][2], s[1][3])));
      float m23 = fmaxf(fmaxf(fmaxf(s[2][0], s[2][1]), fmaxf(s[2][2], s[2][3])),
                        fmaxf(fmaxf(s[3][0], s[3][1]), fmaxf(s[3][2], s[3][3])));
      float mx = fmaxf(m01, m23);
      mx = fmaxf(mx, __shfl_xor(mx, 16));
      mx = fmaxf(mx, __shfl_xor(mx, 32));
      const bool skip = (__ballot(mx <= mrow + 8.0f) == ~0ull);
      float al = 1.0f;
      if (!skip) {
        const float mnew = fmaxf(mrow, mx);
        al = exp2f(mrow - mnew);
        mrow = mnew;
      }
      float sum = 0.f;
#pragma unroll
      for (int ni = 0; ni < 4; ++ni)
#pragma unroll
        for (int r = 0; r < 4; ++r) {
          const float p = exp2f(s[ni][r] - mrow);
          s[ni][r] = p;
          sum += p;
        }
      sum += __shfl_xor(sum, 16);
      sum += __shfl_xor(sum, 32);
      lrow = skip ? (lrow + sum) : (lrow * al + sum);
      // pack P to bf16 pairs: pk[4*kc + {0..3}] = A-frag dwords for PV k-chunk kc
      u32 pk[8];
#pragma unroll
      for (int ni = 0; ni < 4; ++ni) {
        pk[ni * 2] = cvtpk_bf16(s[ni][0], s[ni][1]);
        pk[ni * 2 + 1] = cvtpk_bf16(s[ni][2], s[ni][3]);
      }
      if (!skip) {
        f32x4 av;   // alpha redistributed to output-row layout
#pragma unroll
        for (int r = 0; r < 4; ++r) av[r] = bperm_f(idxR[r], al);
#pragma unroll
        for (int i = 0; i < 8; ++i) o[i] *= av;
      }

      // O += P V, kc=0 from prefetched vf
      union { u32 u[4]; short8 v; } a0u, a1u;
#pragma unroll
      for (int t = 0; t < 4; ++t) { a0u.u[t] = pk[t]; a1u.u[t] = pk[4 + t]; }
      __builtin_amdgcn_s_setprio(1);
#pragma unroll
      for (int ds = 0; ds < 8; ++ds)
        o[ds] = __builtin_amdgcn_mfma_f32_16x16x32_bf16(a0u.v, vf[ds], o[ds], 0, 0, 0);
      __builtin_amdgcn_s_setprio(0);
      // reload vf with kc=1 frags (WAR on regs resolves after PV0 issue)
#pragma unroll
      for (int ds = 0; ds < 8; ++ds) vf[ds] = *(const short8*)(vp + ds * 1024 + 32);
      __builtin_amdgcn_s_setprio(1);
#pragma unroll
      for (int ds = 0; ds < 8; ++ds)
        o[ds] = __builtin_amdgcn_mfma_f32_16x16x32_bf16(a1u.v, vf[ds], o[ds], 0, 0, 0);
      __builtin_amdgcn_s_setprio(0);
    }
    __syncthreads();   // kt+1 stage complete; buf[cur] reads done before overwrite
    cur ^= 1;
  }

  // epilogue
  {
    float linv[4];
#pragma unroll
    for (int r = 0; r < 4; ++r) linv[r] = 1.0f / bperm_f(idxR[r], lrow);
#pragma unroll
    for (int r = 0; r < 4; ++r) {
      const int qr = R + ww * 16 + quad * 4 + r;
      float* op = Out + ((size_t)(h * SEQ + qr)) * HD + l16;
#pragma unroll
      for (int ds = 0; ds < 8; ++ds) op[ds * 16] = o[ds][r] * linv[r];
    }
  }
}

// ---------------- fallback flash (round-3/4 passing version, inline dequant) --------
__global__ __launch_bounds__(256, 2) void flash_fb(const float* __restrict__ Q,
                                                   const float* __restrict__ K,
                                                   const float* __restrict__ V,
                                                   const u32* __restrict__ ctrl,
                                                   const float* __restrict__ kscale,
                                                   const float* __restrict__ vscale,
                                                   float* __restrict__ Out) {
  __shared__ u16 ks[64][136];
  __shared__ u16 vt[128][72];
  __shared__ u16 pl[4][16][72];
  const int blk = blockIdx.x;
  const int h = blk >> 5;
  const int qt = 31 - (blk & 31);
  const int qb = qt << 6;
  const int tid = threadIdx.x;
  const int w = tid >> 6, lane = tid & 63;
  const int l16 = lane & 15, quad = lane >> 4;
  const float SM_SCALE = 0.08838834764831843f;
  const float NEG = -30000.0f;
  const u32 tK = ctrl[0];
  const u64 KrK = (((u64)ctrl[2]) << 32) | ctrl[3];
  const u32 tV = ctrl[8];
  const u64 KrV = (((u64)ctrl[10]) << 32) | ctrl[11];
  const int cch = (tid & 15) * 8;
  float ksc[8], vsc[8];
#pragma unroll
  for (int j = 0; j < 8; ++j) {
    ksc[j] = kscale[h * HD + cch + j];
    vsc[j] = vscale[h * HD + cch + j];
  }
  short8 qf[4];
  {
    const float* qp = Q + ((size_t)(h * SEQ + qb + w * 16 + l16)) * HD + quad * 8;
#pragma unroll
    for (int c = 0; c < 4; ++c) {
      f32x4 a = *(const f32x4*)(qp + c * 32);
      f32x4 b = *(const f32x4*)(qp + c * 32 + 4);
#pragma unroll
      for (int j = 0; j < 4; ++j) {
        qf[c][j] = (short)f2bf(a[j]);
        qf[c][4 + j] = (short)f2bf(b[j]);
      }
    }
  }
  f32x4 o[8];
#pragma unroll
  for (int i = 0; i < 8; ++i) o[i] = (f32x4){0.f, 0.f, 0.f, 0.f};
  float mrow[4], lrow[4];
#pragma unroll
  for (int r = 0; r < 4; ++r) { mrow[r] = NEG; lrow[r] = 0.f; }
  const int ktiles = qt + 1;
  for (int kt = 0; kt < ktiles; ++kt) {
    const int kb = kt << 6;
    __syncthreads();
    {
      const int r0 = tid >> 4;
      const float* kp = K + (size_t)(h * SEQ + kb) * HD;
#pragma unroll
      for (int i = 0; i < 4; ++i) {
        const int row = r0 + i * 16;
        f32x4 x0 = *(const f32x4*)(kp + (size_t)row * HD + cch);
        f32x4 x1 = *(const f32x4*)(kp + (size_t)row * HD + cch + 4);
        const u32 bidx = ((u32)(h * SEQ + kb + row) << 7) + (u32)cch;
        short8 yv;
#pragma unroll
        for (int j = 0; j < 4; ++j) {
          yv[j]     = (short)f2bf(dqf(x0[j], tK, KrK, bidx + j,     false, ksc[j]));
          yv[4 + j] = (short)f2bf(dqf(x1[j], tK, KrK, bidx + 4 + j, false, ksc[4 + j]));
        }
        *(short8*)(&ks[row][cch]) = yv;
      }
    }
    {
      const float* vp = V + (size_t)(h * SEQ + kb) * HD;
#pragma unroll
      for (int i = 0; i < 4; ++i) {
        const int tchunk = tid + i * 256;
        const int s = tchunk >> 4;
        const int tok = kb + s;
        const bool sink = tok < 4;
        f32x4 x0 = *(const f32x4*)(vp + (size_t)s * HD + cch);
        f32x4 x1 = *(const f32x4*)(vp + (size_t)s * HD + cch + 4);
        const u32 bidx = ((u32)(h * SEQ + tok) << 7) + (u32)cch;
#pragma unroll
        for (int j = 0; j < 4; ++j) {
          vt[cch + j][s]     = f2bf(dqf(x0[j], tV, KrV, bidx + j,     sink, vsc[j]));
          vt[cch + 4 + j][s] = f2bf(dqf(x1[j], tV, KrV, bidx + 4 + j, sink, vsc[4 + j]));
        }
      }
    }
    __syncthreads();
    f32x4 sa[4];
#pragma unroll
    for (int ni = 0; ni < 4; ++ni) {
      f32x4 acc = (f32x4){0.f, 0.f, 0.f, 0.f};
#pragma unroll
      for (int c = 0; c < 4; ++c) {
        short8 kf = *(const short8*)(&ks[ni * 16 + l16][c * 32 + quad * 8]);
        acc = __builtin_amdgcn_mfma_f32_16x16x32_bf16(qf[c], kf, acc, 0, 0, 0);
      }
      sa[ni] = acc;
    }
    const bool diag = (kb == qb);
#pragma unroll
    for (int ni = 0; ni < 4; ++ni)
#pragma unroll
      for (int r = 0; r < 4; ++r) {
        float sv = sa[ni][r] * SM_SCALE;
        if (diag) {
          const int qr = w * 16 + quad * 4 + r;
          const int kc = ni * 16 + l16;
          if (kc > qr) sv = NEG;
        }
        sa[ni][r] = sv;
      }
    float alpha[4];
#pragma unroll
    for (int r = 0; r < 4; ++r) {
      float mx = fmaxf(fmaxf(sa[0][r], sa[1][r]), fmaxf(sa[2][r], sa[3][r]));
      mx = fmaxf(mx, __shfl_xor(mx, 1));
      mx = fmaxf(mx, __shfl_xor(mx, 2));
      mx = fmaxf(mx, __shfl_xor(mx, 4));
      mx = fmaxf(mx, __shfl_xor(mx, 8));
      const float mn = fmaxf(mrow[r], mx);
      alpha[r] = __expf(mrow[r] - mn);
      mrow[r] = mn;
      float sum = 0.f;
#pragma unroll
      for (int ni = 0; ni < 4; ++ni) {
        const float p = __expf(sa[ni][r] - mn);
        sa[ni][r] = p;
        sum += p;
      }
      sum += __shfl_xor(sum, 1);
      sum += __shfl_xor(sum, 2);
      sum += __shfl_xor(sum, 4);
      sum += __shfl_xor(sum, 8);
      lrow[r] = lrow[r] * alpha[r] + sum;
    }
#pragma unroll
    for (int ni = 0; ni < 4; ++ni)
#pragma unroll
      for (int r = 0; r < 4; ++r)
        pl[w][quad * 4 + r][ni * 16 + l16] = f2bf(sa[ni][r]);
    __syncthreads();
#pragma unroll
    for (int i = 0; i < 8; ++i)
#pragma unroll
      for (int r = 0; r < 4; ++r) o[i][r] *= alpha[r];
#pragma unroll
    for (int kc = 0; kc < 2; ++kc) {
      short8 af = *(const short8*)(&pl[w][l16][kc * 32 + quad * 8]);
#pragma unroll
      for (int ds = 0; ds < 8; ++ds) {
        short8 vf = *(const short8*)(&vt[ds * 16 + l16][kc * 32 + quad * 8]);
        o[ds] = __builtin_amdgcn_mfma_f32_16x16x32_bf16(af, vf, o[ds], 0, 0, 0);
      }
    }
  }
#pragma unroll
  for (int r = 0; r < 4; ++r) {
    const float inv = 1.0f / lrow[r];
    const int qr = qb + w * 16 + quad * 4 + r;
    float* op = Out + ((size_t)(h * SEQ + qr)) * HD + l16;
#pragma unroll
    for (int ds = 0; ds < 8; ++ds) op[ds * 16] = o[ds][r] * inv;
  }
}

// ---------------- launcher ----------------
extern "C" void kernel_launch(void* const* d_in, const int* in_sizes, int n_in,
                              void* d_out, int out_size, void* d_ws, size_t ws_size,
                              hipStream_t stream) {
  const float* q = (const float*)d_in[0];
  const float* k = (const float*)d_in[1];
  const float* v = (const float*)d_in[2];
  float* out = (float*)d_out;
  char* ws = (char*)d_ws;

  u32* ctrl    = (u32*)ws;                               // 256 B
  u32* histK   = (u32*)(ws + 256);                       // 128 KB
  u32* histV   = (u32*)(ws + 256 + 131072);              // 128 KB
  u32* kmax    = (u32*)(ws + 262400);                    // 16 KB
  u32* vmax    = (u32*)(ws + 278784);                    // 16 KB
  const size_t ZERO_BYTES = 295168;                      // ctrl+hists+maxes
  float* kscale = (float*)(ws + 295168);                 // 16 KB
  float* vscale = (float*)(ws + 311552);                 // 16 KB
  u32* caK = (u32*)(ws + 327936);                        // 4x32 KB
  u32* ciK = caK + CAND_CAP;
  u32* caV = ciK + CAND_CAP;
  u32* ciV = caV + CAND_CAP;
  u16* krec  = (u16*)(ws + 458752);                      // 16 MB
  u16* vrecT = (u16*)(ws + 458752 + 16777216);           // 16 MB
  const size_t NEED = 458752 + 2ull * 16777216;

  hipMemsetAsync(ws, 0, ZERO_BYTES, stream);
  hist_kernel<<<256, 256, 0, stream>>>(k, v, histK, histV);
  thresh_kernel<<<2, 256, 0, stream>>>(histK, histV, ctrl);
  candmax_kernel<<<dim3(256, 2), 256, 0, stream>>>(k, v, ctrl, caK, ciK, caV, ciV, kmax, vmax);
  ksel_kernel<<<dim3(32, 2), 256, 0, stream>>>(ctrl, caK, ciK, caV, ciV);
  maxfix_scale_kernel<<<2, 256, 0, stream>>>(ctrl, caK, ciK, caV, ciV, kmax, vmax, kscale, vscale);
  if (ws_size >= NEED) {
    recon_kv_kernel<<<3072, 256, 0, stream>>>(k, v, ctrl, kscale, vscale, krec, vrecT);
    flash_pre<<<512, 512, 0, stream>>>(q, krec, vrecT, out);
  } else {
    flash_fb<<<32 * 32, 256, 0, stream>>>(q, k, v, ctrl, kscale, vscale, out);
  }
}

// Round 6
// 378.642 us; speedup vs baseline: 1.0880x; 1.0880x over previous
//
#include <hip/hip_runtime.h>

typedef unsigned short u16;
typedef unsigned int u32;
typedef unsigned long long u64;
typedef __attribute__((ext_vector_type(8))) short short8;
typedef __attribute__((ext_vector_type(4))) float f32x4;

#define N_ELEM 8388608
#define NH 32
#define SEQ 2048
#define HD 128
#define KTOP 32768u
#define CAND_CAP 8192u

__device__ __forceinline__ u16 f2bf(float f) {
  union { float f; u32 u; } v; v.f = f;
  u32 r = v.u + 0x7fffu + ((v.u >> 16) & 1u);
  return (u16)(r >> 16);
}

// fp32 quant-dequant, exact reference semantics; keeps outliers & sinks verbatim
__device__ __forceinline__ float dqf(float x, u32 t, u64 Kr, u32 idx, bool sink, float scale) {
  union { float f; u32 u; } w; w.f = x;
  const u32 ab = w.u & 0x7fffffffu;
  const u32 bin = ab >> 16;
  const bool keep = sink || (bin > t) ||
                    (bin == t && ((((u64)ab) << 32) | (u32)(~idx)) >= Kr);
  if (keep) return x;
  float q = rintf(x / scale);            // round-half-even == jnp.round
  q = fminf(fmaxf(q, -8.0f), 7.0f);
  return q * scale;
}

// packed fp32->bf16 RNE (identical rounding to f2bf); no builtin on gfx950
__device__ __forceinline__ u32 cvtpk_bf16(float lo, float hi) {
  u32 r;
  asm("v_cvt_pk_bf16_f32 %0, %1, %2" : "=v"(r) : "v"(lo), "v"(hi));
  return r;
}

__device__ __forceinline__ float bperm_f(int ibyte, float x) {
  union { float f; int i; } a, b;
  a.f = x;
  b.i = __builtin_amdgcn_ds_bpermute(ibyte, a.i);
  return b.f;
}

__device__ __forceinline__ u32 aload(const u32* p) {
  return __hip_atomic_load(p, __ATOMIC_RELAXED, __HIP_MEMORY_SCOPE_AGENT);
}

// ---------------- K1: 32768-bin histogram + fused threshold scan (last block) -------
__global__ __launch_bounds__(256) void hist_kernel(const float* __restrict__ k,
                                                   const float* __restrict__ v,
                                                   u32* __restrict__ histK,
                                                   u32* __restrict__ histV,
                                                   u32* __restrict__ ctrl) {
  __shared__ u32 sh[16384];
  __shared__ u32 lastf, sh_chunk, sh_cum;
  const int tensor = blockIdx.x >> 7;
  const int bid = blockIdx.x & 127;
  const float* src = tensor ? v : k;
  u32* gh = tensor ? histV : histK;
  for (int i = threadIdx.x; i < 16384; i += 256) sh[i] = 0;
  __syncthreads();
  const int per = N_ELEM / 128;  // 65536
  const int base = bid * per;
  for (int i = threadIdx.x; i < per / 4; i += 256) {
    f32x4 x = *(const f32x4*)(src + base + i * 4);
#pragma unroll
    for (int j = 0; j < 4; ++j) {
      union { float f; u32 u; } w; w.f = x[j];
      u32 b = (w.u & 0x7fffffffu) >> 16;
      atomicAdd(&sh[b >> 1], 1u << ((b & 1u) * 16));
    }
  }
  __syncthreads();
  for (int i = threadIdx.x; i < 16384; i += 256) {
    u32 w = sh[i];
    u32 lo = w & 0xffffu, hi = w >> 16;
    if (lo) atomicAdd(&gh[2 * i], lo);
    if (hi) atomicAdd(&gh[2 * i + 1], hi);
  }
  // ---- fused threshold scan: last block per tensor (release: fence -> sync -> atomic)
  __threadfence();
  __syncthreads();
  if (threadIdx.x == 0)
    lastf = (atomicAdd(&ctrl[16 + tensor], 1u) == 127u) ? 1u : 0u;
  __syncthreads();
  if (!lastf) return;
  __threadfence();   // acquire side
  u32* c = ctrl + tensor * 8;
  u32* part = sh;          // reuse LDS
  u32* bins = sh + 256;
  u32 s = 0;
  for (int i = 0; i < 128; ++i)
    s += aload(&gh[threadIdx.x * 128 + i]);
  part[threadIdx.x] = s;
  __syncthreads();
  if (threadIdx.x == 0) {
    u32 cum = 0;
    int chunk = 255;
    while (chunk > 0 && cum + part[chunk] < KTOP) { cum += part[chunk]; --chunk; }
    sh_chunk = (u32)chunk; sh_cum = cum;
  }
  __syncthreads();
  const u32 chunk = sh_chunk;
  if (threadIdx.x < 128) bins[threadIdx.x] = aload(&gh[chunk * 128 + threadIdx.x]);
  __syncthreads();
  if (threadIdx.x == 0) {
    u32 cum = sh_cum;
    int b = 127;
    while (b > 0 && cum + bins[b] < KTOP) { cum += bins[b]; --b; }
    c[0] = chunk * 128 + (u32)b;
    c[1] = KTOP - cum;
  }
}

// ---------------- K3: fused candidate gather + per-(h,d) max over bin<t -------------
// grid (256, 2): head h = bx>>3, row-eighth = bx&7 (256 rows/block) -> 2 blocks/CU.
__global__ __launch_bounds__(256) void candmax_kernel(const float* __restrict__ k,
                                                      const float* __restrict__ v,
                                                      u32* __restrict__ ctrl,
                                                      u32* __restrict__ caK, u32* __restrict__ ciK,
                                                      u32* __restrict__ caV, u32* __restrict__ ciV,
                                                      u32* __restrict__ kmax,
                                                      u32* __restrict__ vmax) {
  __shared__ u32 colmax[128];
  const int tensor = blockIdx.y;
  const float* src = tensor ? v : k;
  u32* ca = tensor ? caV : caK;
  u32* ci = tensor ? ciV : ciK;
  u32* cnt = &ctrl[tensor * 8 + 4];
  u32* mbuf = tensor ? vmax : kmax;
  const u32 t = ctrl[tensor * 8 + 0];
  const int h = blockIdx.x >> 3;
  const int q8 = blockIdx.x & 7;
  const int tid = threadIdx.x;
  if (tid < 128) colmax[tid] = 0;
  __syncthreads();
  const int c0 = 4 * (tid & 31);
  u32 mx[4] = {0, 0, 0, 0};
  for (int p = 0; p < 32; ++p) {
    const int s = q8 * 256 + p * 8 + (tid >> 5);
    const u32 idx = ((u32)(h * SEQ + s) << 7) + (u32)c0;
    f32x4 x = *(const f32x4*)(src + idx);
    const bool skipmax = (tensor == 1 && s < 4);
#pragma unroll
    for (int j = 0; j < 4; ++j) {
      union { float f; u32 u; } w; w.f = x[j];
      const u32 ab = w.u & 0x7fffffffu;
      const u32 bin = ab >> 16;
      if (bin == t) {
        u32 slot = atomicAdd(cnt, 1u);
        if (slot < CAND_CAP) { ca[slot] = ab; ci[slot] = idx + j; }
      }
      if (bin < t && !skipmax && ab > mx[j]) mx[j] = ab;
    }
  }
#pragma unroll
  for (int j = 0; j < 4; ++j) atomicMax(&colmax[c0 + j], mx[j]);
  __syncthreads();
  if (tid < 128) atomicMax(&mbuf[h * HD + tid], colmax[tid]);
}

// ---------------- K4: Kr selection + fused maxfix/scale (last block per tensor) -----
__global__ __launch_bounds__(256) void ksel_kernel(u32* __restrict__ ctrl,
                                                   const u32* __restrict__ caK, const u32* __restrict__ ciK,
                                                   const u32* __restrict__ caV, const u32* __restrict__ ciV,
                                                   u32* __restrict__ kmax, u32* __restrict__ vmax,
                                                   float* __restrict__ kscale, float* __restrict__ vscale) {
  __shared__ u64 keys[CAND_CAP];
  __shared__ u32 lastf;
  const int tensor = blockIdx.y;
  u32* c = ctrl + tensor * 8;
  const u32 r = c[1];
  u32 T = c[4];
  if (T > CAND_CAP) T = CAND_CAP;
  const u32* ca = tensor ? caV : caK;
  const u32* ci = tensor ? ciV : ciK;
  for (u32 j = threadIdx.x; j < T; j += 256)
    keys[j] = (((u64)ca[j]) << 32) | (u32)(~ci[j]);
  __syncthreads();
  for (u32 i = blockIdx.x * 256 + threadIdx.x; i < T; i += 32 * 256) {
    const u64 ki = keys[i];
    u32 cnt = 0;
    for (u32 j = 0; j < T; ++j) cnt += (keys[j] > ki) ? 1u : 0u;
    if (cnt == r - 1) { c[2] = (u32)(ki >> 32); c[3] = (u32)ki; }
  }
  // ---- fused maxfix + scale: last block per tensor
  __threadfence();
  __syncthreads();
  if (threadIdx.x == 0)
    lastf = (atomicAdd(&ctrl[18 + tensor], 1u) == 31u) ? 1u : 0u;
  __syncthreads();
  if (!lastf) return;
  __threadfence();   // acquire: Kr stores from other blocks now visible
  const u64 Kr = (((u64)aload(&c[2])) << 32) | aload(&c[3]);
  u32* mbuf = tensor ? vmax : kmax;
  for (u32 i = threadIdx.x; i < T; i += 256) {
    const u64 kk = keys[i];                               // LDS copy of (ab, ~idx)
    const u32 ab = (u32)(kk >> 32);
    const u32 idx = ~((u32)kk);
    if (kk >= Kr) continue;                               // outlier -> excluded
    if (tensor == 1 && ((idx >> 7) & 2047) < 4) continue; // V sink -> excluded
    atomicMax(&mbuf[(idx >> 18) * HD + (idx & 127)], ab);
  }
  __syncthreads();
  float* sbuf = tensor ? vscale : kscale;
  for (int i = threadIdx.x; i < NH * HD; i += 256) {
    union { u32 u; float f; } a; a.u = aload(&mbuf[i]);
    sbuf[i] = fmaxf(a.f, 1e-6f) / 7.0f;
  }
}

// ---------------- K6: reconstruct K -> krec (row-major) AND V -> vrecT, one launch ---
// blocks [0,2048): K path (grid-stride). blocks [2048,3072): V transpose path.
__global__ __launch_bounds__(256) void recon_kv_kernel(const float* __restrict__ K,
                                                       const float* __restrict__ V,
                                                       const u32* __restrict__ ctrl,
                                                       const float* __restrict__ kscale,
                                                       const float* __restrict__ vscale,
                                                       u16* __restrict__ krec,
                                                       u16* __restrict__ vrecT) {
  __shared__ u32 ld[64][65];   // [d-pair][s_local], pad 64->65 (V path only)
  const int tid = threadIdx.x;
  if (blockIdx.x < 2048) {
    const u32 t = ctrl[0];
    const u64 Kr = (((u64)ctrl[2]) << 32) | ctrl[3];
    const int stride = 2048 * 256;
    for (int i = blockIdx.x * 256 + tid; i < N_ELEM / 4; i += stride) {
      const u32 e = (u32)i * 4;
      const u32 d0 = e & 127, h = e >> 18;
      f32x4 x = *(const f32x4*)(K + e);
      f32x4 sc = *(const f32x4*)(kscale + h * HD + d0);
      u16 y[4];
#pragma unroll
      for (int j = 0; j < 4; ++j) y[j] = f2bf(dqf(x[j], t, Kr, e + j, false, sc[j]));
      *(u32*)(krec + e) = ((u32)y[0]) | (((u32)y[1]) << 16);
      *(u32*)(krec + e + 2) = ((u32)y[2]) | (((u32)y[3]) << 16);
    }
  } else {
    const int b = blockIdx.x - 2048;
    const u32 t = ctrl[8];
    const u64 Kr = (((u64)ctrl[10]) << 32) | ctrl[11];
    const int h = b >> 5, sb = b & 31;
    const int d0 = 4 * (tid & 31);
    f32x4 sc = *(const f32x4*)(vscale + h * HD + d0);
#pragma unroll
    for (int p = 0; p < 8; ++p) {
      const int sl = p * 8 + (tid >> 5);
      const int tok = sb * 64 + sl;
      const bool sink = tok < 4;
      const u32 idx = ((u32)(h * SEQ + tok) << 7) + (u32)d0;
      f32x4 x = *(const f32x4*)(V + idx);
      u16 y[4];
#pragma unroll
      for (int j = 0; j < 4; ++j) y[j] = f2bf(dqf(x[j], t, Kr, idx + j, sink, sc[j]));
      ld[(d0 >> 1)][sl] = ((u32)y[0]) | (((u32)y[1]) << 16);
      ld[(d0 >> 1) + 1][sl] = ((u32)y[2]) | (((u32)y[3]) << 16);
    }
    __syncthreads();
    const int d = tid >> 1, so = (tid & 1) * 32, e = d & 1;
    u16* outp = vrecT + (size_t)(h * 32 + sb) * 8192 + d * 64 + so;
#pragma unroll
    for (int i = 0; i < 4; ++i) {
      short8 y;
#pragma unroll
      for (int m = 0; m < 8; ++m) {
        const u32 w2 = ld[d >> 1][so + i * 8 + m];
        y[m] = (short)(u16)(w2 >> (16 * e));
      }
      *(short8*)(outp + i * 8) = y;
    }
  }
}

// ---------------- K8: flash attention, swapped-QK, 8-wave blocks (R4 + defer-max) ---
// Block = head h x pair a: q-tiles {a, 31-a}; 512 threads: waves 0-3 own subtile A,
// waves 4-7 own subtile B; 2 blocks/CU = 16 waves/CU.
// QK^T as mfma(K, Q): lane owns ONE q-row (l16); bit-shuffled K rows make the lane's
// 16 scores exactly the PV A-fragment after v_cvt_pk_bf16_f32 (no P LDS round-trip).
// XCD swizzle: 4 heads per XCD -> per-XCD K/V working set = 4 MB = L2 size.
// T13 defer-max: skip O-rescale while tile max grows < 8 (exp2 domain, P <= 256).
#define SC_QK 0.12751743f   // log2(e)/sqrt(128): exp2-domain softmax
#define NEGS -30000.0f

__global__ __launch_bounds__(512, 4) void flash_pre(const float* __restrict__ Q,
                                                    const u16* __restrict__ krec,
                                                    const u16* __restrict__ vrecT,
                                                    float* __restrict__ Out) {
  __shared__ u16 ks[64][132];     // K tile (permuted token rows x channel)
  __shared__ u16 vt[128][68];     // V^T tile (channel x token)

  // XCD swizzle: xcd = b&7 serves heads {xcd, xcd+8, xcd+16, xcd+24}
  const int b = blockIdx.x;       // 512 = 32 heads x 16 pairs
  const int h = (b & 7) + 8 * ((b >> 3) >> 4);
  const int pa = (b >> 3) & 15;
  const int RA = pa << 6;          // q-tile A row base (0..960)
  const int RB = (31 - pa) << 6;   // q-tile B row base (1024..1984)
  const int tid = threadIdx.x;
  const int w = tid >> 6, lane = tid & 63;
  const int ww = w & 3;            // wave index within subtile group
  const int R = (w >> 2) ? RB : RA;  // this wave's subtile row base
  const int l16 = lane & 15, quad = lane >> 4;
  const int qrow16 = ww * 16 + l16;  // this lane's q-row within the 64-row subtile

  int idxR[4];                     // bpermute byte-idx: same-quad lane with l16 = quad*4+r
#pragma unroll
  for (int r = 0; r < 4; ++r) idxR[r] = ((lane & 48) | (quad * 4 + r)) << 2;

  // Q fragment for this wave's subtile (B-operand: col = q = l16)
  short8 qf[4];
  {
    const float* qp = Q + ((size_t)(h * SEQ + R + ww * 16 + l16)) * HD + quad * 8;
#pragma unroll
    for (int c = 0; c < 4; ++c) {
      f32x4 a = *(const f32x4*)(qp + c * 32);
      f32x4 bb = *(const f32x4*)(qp + c * 32 + 4);
      union { u32 u[4]; short8 v; } t;
      t.u[0] = cvtpk_bf16(a[0], a[1]);
      t.u[1] = cvtpk_bf16(a[2], a[3]);
      t.u[2] = cvtpk_bf16(bb[0], bb[1]);
      t.u[3] = cvtpk_bf16(bb[2], bb[3]);
      qf[c] = t.v;
    }
  }

  f32x4 o[8];
#pragma unroll
  for (int i = 0; i < 8; ++i) o[i] = (f32x4){0.f, 0.f, 0.f, 0.f};
  float mrow = NEGS, lrow = 0.f;

  // staging thread mapping (512 threads) + prefetch registers
  const int krow = tid >> 3, kqo = (tid & 7) * 16;   // K: 64 rows x 256B, 8 thr/row
  // token->LDS-row bit shuffle: x = [t5 t2 | t4 t3 | t1 t0]
  const int krp = (krow & 35) | (((krow >> 2) & 1) << 4) |
                  (((krow >> 4) & 1) << 3) | (((krow >> 3) & 1) << 2);
  // V^T: 128 rows x 64 u16, 4 thr/row; thread covers {vco, vco+32}, vco in {0,8,16,24}
  const int vd = tid >> 2, vco = (tid & 3) * 8;
  const u16* kbase = krec + ((size_t)h * SEQ + krow) * HD + kqo;
  const u16* vbase = vrecT + (size_t)h * 32 * 8192 + vd * 64 + vco;
  short8 kr[2], vr, vr2;
  kr[0] = *(const short8*)(kbase);
  kr[1] = *(const short8*)(kbase + 8);
  vr = *(const short8*)(vbase);
  vr2 = *(const short8*)(vbase + 32);

  const int ktiles = (RB >> 6) + 1;   // 17..32
  for (int kt = 0; kt < ktiles; ++kt) {
    const int kb = kt << 6;
    __syncthreads();                  // previous compute done with LDS
    *(short8*)(&ks[krp][kqo]) = kr[0];
    *(short8*)(&ks[krp][kqo + 8]) = kr[1];
    *(short8*)(&vt[vd][vco]) = vr;
    *(short8*)(&vt[vd][vco + 32]) = vr2;
    __syncthreads();
    if (kt + 1 < ktiles) {            // prefetch next tile under this tile's compute
      const u16* kp = kbase + (size_t)(kt + 1) * 64 * HD;
      const u16* vp = vbase + (size_t)(kt + 1) * 8192;
      kr[0] = *(const short8*)(kp);
      kr[1] = *(const short8*)(kp + 8);
      vr = *(const short8*)(vp);
      vr2 = *(const short8*)(vp + 32);
    }
    if (kb <= R) {
      // S^T = K Q^T: A = K frags from LDS, B = Q regs
      f32x4 s[4];
      __builtin_amdgcn_s_setprio(1);
#pragma unroll
      for (int ni = 0; ni < 4; ++ni) {
        f32x4 acc = (f32x4){0.f, 0.f, 0.f, 0.f};
#pragma unroll
        for (int c = 0; c < 4; ++c) {
          short8 kf = *(const short8*)(&ks[ni * 16 + l16][c * 32 + quad * 8]);
          acc = __builtin_amdgcn_mfma_f32_16x16x32_bf16(kf, qf[c], acc, 0, 0, 0);
        }
        s[ni] = acc;
      }
      __builtin_amdgcn_s_setprio(0);

      // softmax with defer-max; token of s[ni][r] = (ni>>1)*32 + quad*8 + (ni&1)*4 + r
      const bool diag = (kb == R);
#pragma unroll
      for (int ni = 0; ni < 4; ++ni)
#pragma unroll
        for (int r = 0; r < 4; ++r) {
          float sv = s[ni][r] * SC_QK;
          const int tokl = ((ni >> 1) << 5) | (quad << 3) | ((ni & 1) << 2) | r;
          if (diag && tokl > qrow16) sv = NEGS;
          s[ni][r] = sv;
        }
      float m01 = fmaxf(fmaxf(fmaxf(s[0][0], s[0][1]), fmaxf(s[0][2], s[0][3])),
                        fmaxf(fmaxf(s[1][0], s[1][1]), fmaxf(s[1][2], s[1][3])));
      float m23 = fmaxf(fmaxf(fmaxf(s[2][0], s[2][1]), fmaxf(s[2][2], s[2][3])),
                        fmaxf(fmaxf(s[3][0], s[3][1]), fmaxf(s[3][2], s[3][3])));
      float mx = fmaxf(m01, m23);
      mx = fmaxf(mx, __shfl_xor(mx, 16));
      mx = fmaxf(mx, __shfl_xor(mx, 32));
      const bool skip = (__ballot(mx <= mrow + 8.0f) == ~0ull);
      float al = 1.0f;
      if (!skip) {
        const float mnew = fmaxf(mrow, mx);
        al = exp2f(mrow - mnew);
        mrow = mnew;
      }
      float sum = 0.f;
#pragma unroll
      for (int ni = 0; ni < 4; ++ni)
#pragma unroll
        for (int r = 0; r < 4; ++r) {
          const float p = exp2f(s[ni][r] - mrow);
          s[ni][r] = p;
          sum += p;
        }
      sum += __shfl_xor(sum, 16);
      sum += __shfl_xor(sum, 32);
      lrow = skip ? (lrow + sum) : (lrow * al + sum);
      // pack P to bf16 pairs: pk[4*kc + {0..3}] = A-frag dwords for PV k-chunk kc
      u32 pk[8];
#pragma unroll
      for (int ni = 0; ni < 4; ++ni) {
        pk[ni * 2] = cvtpk_bf16(s[ni][0], s[ni][1]);
        pk[ni * 2 + 1] = cvtpk_bf16(s[ni][2], s[ni][3]);
      }
      if (!skip) {
        f32x4 av;   // alpha redistributed to output-row layout
#pragma unroll
        for (int r = 0; r < 4; ++r) av[r] = bperm_f(idxR[r], al);
#pragma unroll
        for (int i = 0; i < 8; ++i) o[i] *= av;
      }

      // O += P V  (P A-frags are lane-local registers; V frags from LDS)
      __builtin_amdgcn_s_setprio(1);
#pragma unroll
      for (int kc = 0; kc < 2; ++kc) {
        union { u32 u[4]; short8 v; } au;
#pragma unroll
        for (int t = 0; t < 4; ++t) au.u[t] = pk[kc * 4 + t];
        const short8 af = au.v;
#pragma unroll
        for (int ds = 0; ds < 8; ++ds) {
          short8 vf = *(const short8*)(&vt[ds * 16 + l16][kc * 32 + quad * 8]);
          o[ds] = __builtin_amdgcn_mfma_f32_16x16x32_bf16(af, vf, o[ds], 0, 0, 0);
        }
      }
      __builtin_amdgcn_s_setprio(0);
    }
  }

  // epilogue
  {
    float linv[4];
#pragma unroll
    for (int r = 0; r < 4; ++r) linv[r] = 1.0f / bperm_f(idxR[r], lrow);
#pragma unroll
    for (int r = 0; r < 4; ++r) {
      const int qr = R + ww * 16 + quad * 4 + r;
      float* op = Out + ((size_t)(h * SEQ + qr)) * HD + l16;
#pragma unroll
      for (int ds = 0; ds < 8; ++ds) op[ds * 16] = o[ds][r] * linv[r];
    }
  }
}

// ---------------- fallback flash (round-3/4 passing version, inline dequant) --------
__global__ __launch_bounds__(256, 2) void flash_fb(const float* __restrict__ Q,
                                                   const float* __restrict__ K,
                                                   const float* __restrict__ V,
                                                   const u32* __restrict__ ctrl,
                                                   const float* __restrict__ kscale,
                                                   const float* __restrict__ vscale,
                                                   float* __restrict__ Out) {
  __shared__ u16 ks[64][136];
  __shared__ u16 vt[128][72];
  __shared__ u16 pl[4][16][72];
  const int blk = blockIdx.x;
  const int h = blk >> 5;
  const int qt = 31 - (blk & 31);
  const int qb = qt << 6;
  const int tid = threadIdx.x;
  const int w = tid >> 6, lane = tid & 63;
  const int l16 = lane & 15, quad = lane >> 4;
  const float SM_SCALE = 0.08838834764831843f;
  const float NEG = -30000.0f;
  const u32 tK = ctrl[0];
  const u64 KrK = (((u64)ctrl[2]) << 32) | ctrl[3];
  const u32 tV = ctrl[8];
  const u64 KrV = (((u64)ctrl[10]) << 32) | ctrl[11];
  const int cch = (tid & 15) * 8;
  float ksc[8], vsc[8];
#pragma unroll
  for (int j = 0; j < 8; ++j) {
    ksc[j] = kscale[h * HD + cch + j];
    vsc[j] = vscale[h * HD + cch + j];
  }
  short8 qf[4];
  {
    const float* qp = Q + ((size_t)(h * SEQ + qb + w * 16 + l16)) * HD + quad * 8;
#pragma unroll
    for (int c = 0; c < 4; ++c) {
      f32x4 a = *(const f32x4*)(qp + c * 32);
      f32x4 b = *(const f32x4*)(qp + c * 32 + 4);
#pragma unroll
      for (int j = 0; j < 4; ++j) {
        qf[c][j] = (short)f2bf(a[j]);
        qf[c][4 + j] = (short)f2bf(b[j]);
      }
    }
  }
  f32x4 o[8];
#pragma unroll
  for (int i = 0; i < 8; ++i) o[i] = (f32x4){0.f, 0.f, 0.f, 0.f};
  float mrow[4], lrow[4];
#pragma unroll
  for (int r = 0; r < 4; ++r) { mrow[r] = NEG; lrow[r] = 0.f; }
  const int ktiles = qt + 1;
  for (int kt = 0; kt < ktiles; ++kt) {
    const int kb = kt << 6;
    __syncthreads();
    {
      const int r0 = tid >> 4;
      const float* kp = K + (size_t)(h * SEQ + kb) * HD;
#pragma unroll
      for (int i = 0; i < 4; ++i) {
        const int row = r0 + i * 16;
        f32x4 x0 = *(const f32x4*)(kp + (size_t)row * HD + cch);
        f32x4 x1 = *(const f32x4*)(kp + (size_t)row * HD + cch + 4);
        const u32 bidx = ((u32)(h * SEQ + kb + row) << 7) + (u32)cch;
        short8 yv;
#pragma unroll
        for (int j = 0; j < 4; ++j) {
          yv[j]     = (short)f2bf(dqf(x0[j], tK, KrK, bidx + j,     false, ksc[j]));
          yv[4 + j] = (short)f2bf(dqf(x1[j], tK, KrK, bidx + 4 + j, false, ksc[4 + j]));
        }
        *(short8*)(&ks[row][cch]) = yv;
      }
    }
    {
      const float* vp = V + (size_t)(h * SEQ + kb) * HD;
#pragma unroll
      for (int i = 0; i < 4; ++i) {
        const int tchunk = tid + i * 256;
        const int s = tchunk >> 4;
        const int tok = kb + s;
        const bool sink = tok < 4;
        f32x4 x0 = *(const f32x4*)(vp + (size_t)s * HD + cch);
        f32x4 x1 = *(const f32x4*)(vp + (size_t)s * HD + cch + 4);
        const u32 bidx = ((u32)(h * SEQ + tok) << 7) + (u32)cch;
#pragma unroll
        for (int j = 0; j < 4; ++j) {
          vt[cch + j][s]     = f2bf(dqf(x0[j], tV, KrV, bidx + j,     sink, vsc[j]));
          vt[cch + 4 + j][s] = f2bf(dqf(x1[j], tV, KrV, bidx + 4 + j, sink, vsc[4 + j]));
        }
      }
    }
    __syncthreads();
    f32x4 sa[4];
#pragma unroll
    for (int ni = 0; ni < 4; ++ni) {
      f32x4 acc = (f32x4){0.f, 0.f, 0.f, 0.f};
#pragma unroll
      for (int c = 0; c < 4; ++c) {
        short8 kf = *(const short8*)(&ks[ni * 16 + l16][c * 32 + quad * 8]);
        acc = __builtin_amdgcn_mfma_f32_16x16x32_bf16(qf[c], kf, acc, 0, 0, 0);
      }
      sa[ni] = acc;
    }
    const bool diag = (kb == qb);
#pragma unroll
    for (int ni = 0; ni < 4; ++ni)
#pragma unroll
      for (int r = 0; r < 4; ++r) {
        float sv = sa[ni][r] * SM_SCALE;
        if (diag) {
          const int qr = w * 16 + quad * 4 + r;
          const int kc = ni * 16 + l16;
          if (kc > qr) sv = NEG;
        }
        sa[ni][r] = sv;
      }
    float alpha[4];
#pragma unroll
    for (int r = 0; r < 4; ++r) {
      float mx = fmaxf(fmaxf(sa[0][r], sa[1][r]), fmaxf(sa[2][r], sa[3][r]));
      mx = fmaxf(mx, __shfl_xor(mx, 1));
      mx = fmaxf(mx, __shfl_xor(mx, 2));
      mx = fmaxf(mx, __shfl_xor(mx, 4));
      mx = fmaxf(mx, __shfl_xor(mx, 8));
      const float mn = fmaxf(mrow[r], mx);
      alpha[r] = __expf(mrow[r] - mn);
      mrow[r] = mn;
      float sum = 0.f;
#pragma unroll
      for (int ni = 0; ni < 4; ++ni) {
        const float p = __expf(sa[ni][r] - mn);
        sa[ni][r] = p;
        sum += p;
      }
      sum += __shfl_xor(sum, 1);
      sum += __shfl_xor(sum, 2);
      sum += __shfl_xor(sum, 4);
      sum += __shfl_xor(sum, 8);
      lrow[r] = lrow[r] * alpha[r] + sum;
    }
#pragma unroll
    for (int ni = 0; ni < 4; ++ni)
#pragma unroll
      for (int r = 0; r < 4; ++r)
        pl[w][quad * 4 + r][ni * 16 + l16] = f2bf(sa[ni][r]);
    __syncthreads();
#pragma unroll
    for (int i = 0; i < 8; ++i)
#pragma unroll
      for (int r = 0; r < 4; ++r) o[i][r] *= alpha[r];
#pragma unroll
    for (int kc = 0; kc < 2; ++kc) {
      short8 af = *(const short8*)(&pl[w][l16][kc * 32 + quad * 8]);
#pragma unroll
      for (int ds = 0; ds < 8; ++ds) {
        short8 vf = *(const short8*)(&vt[ds * 16 + l16][kc * 32 + quad * 8]);
        o[ds] = __builtin_amdgcn_mfma_f32_16x16x32_bf16(af, vf, o[ds], 0, 0, 0);
      }
    }
  }
#pragma unroll
  for (int r = 0; r < 4; ++r) {
    const float inv = 1.0f / lrow[r];
    const int qr = qb + w * 16 + quad * 4 + r;
    float* op = Out + ((size_t)(h * SEQ + qr)) * HD + l16;
#pragma unroll
    for (int ds = 0; ds < 8; ++ds) op[ds * 16] = o[ds][r] * inv;
  }
}

// ---------------- launcher (6 dispatches: memset, hist+thresh, candmax, ksel+maxfix,
//                  recon, flash) ----------------
extern "C" void kernel_launch(void* const* d_in, const int* in_sizes, int n_in,
                              void* d_out, int out_size, void* d_ws, size_t ws_size,
                              hipStream_t stream) {
  const float* q = (const float*)d_in[0];
  const float* k = (const float*)d_in[1];
  const float* v = (const float*)d_in[2];
  float* out = (float*)d_out;
  char* ws = (char*)d_ws;

  u32* ctrl    = (u32*)ws;                               // 256 B (incl. done-counters 16..19)
  u32* histK   = (u32*)(ws + 256);                       // 128 KB
  u32* histV   = (u32*)(ws + 256 + 131072);              // 128 KB
  u32* kmax    = (u32*)(ws + 262400);                    // 16 KB
  u32* vmax    = (u32*)(ws + 278784);                    // 16 KB
  const size_t ZERO_BYTES = 295168;                      // ctrl+hists+maxes
  float* kscale = (float*)(ws + 295168);                 // 16 KB
  float* vscale = (float*)(ws + 311552);                 // 16 KB
  u32* caK = (u32*)(ws + 327936);                        // 4x32 KB
  u32* ciK = caK + CAND_CAP;
  u32* caV = ciK + CAND_CAP;
  u32* ciV = caV + CAND_CAP;
  u16* krec  = (u16*)(ws + 458752);                      // 16 MB
  u16* vrecT = (u16*)(ws + 458752 + 16777216);           // 16 MB
  const size_t NEED = 458752 + 2ull * 16777216;

  hipMemsetAsync(ws, 0, ZERO_BYTES, stream);
  hist_kernel<<<256, 256, 0, stream>>>(k, v, histK, histV, ctrl);
  candmax_kernel<<<dim3(256, 2), 256, 0, stream>>>(k, v, ctrl, caK, ciK, caV, ciV, kmax, vmax);
  ksel_kernel<<<dim3(32, 2), 256, 0, stream>>>(ctrl, caK, ciK, caV, ciV, kmax, vmax, kscale, vscale);
  if (ws_size >= NEED) {
    recon_kv_kernel<<<3072, 256, 0, stream>>>(k, v, ctrl, kscale, vscale, krec, vrecT);
    flash_pre<<<512, 512, 0, stream>>>(q, krec, vrecT, out);
  } else {
    flash_fb<<<32 * 32, 256, 0, stream>>>(q, k, v, ctrl, kscale, vscale, out);
  }
}

// Round 7
// 361.649 us; speedup vs baseline: 1.1391x; 1.0470x over previous
//
#include <hip/hip_runtime.h>

typedef unsigned short u16;
typedef unsigned int u32;
typedef unsigned long long u64;
typedef __attribute__((ext_vector_type(8))) short short8;
typedef __attribute__((ext_vector_type(4))) float f32x4;

#define N_ELEM 8388608
#define NH 32
#define SEQ 2048
#define HD 128
#define KTOP 32768u
#define CAND_CAP 8192u

__device__ __forceinline__ u16 f2bf(float f) {
  union { float f; u32 u; } v; v.f = f;
  u32 r = v.u + 0x7fffu + ((v.u >> 16) & 1u);
  return (u16)(r >> 16);
}

// fp32 quant-dequant, exact reference semantics; keeps outliers & sinks verbatim
__device__ __forceinline__ float dqf(float x, u32 t, u64 Kr, u32 idx, bool sink, float scale) {
  union { float f; u32 u; } w; w.f = x;
  const u32 ab = w.u & 0x7fffffffu;
  const u32 bin = ab >> 16;
  const bool keep = sink || (bin > t) ||
                    (bin == t && ((((u64)ab) << 32) | (u32)(~idx)) >= Kr);
  if (keep) return x;
  float q = rintf(x / scale);            // round-half-even == jnp.round
  q = fminf(fmaxf(q, -8.0f), 7.0f);
  return q * scale;
}

// packed fp32->bf16 RNE (identical rounding to f2bf); no builtin on gfx950
__device__ __forceinline__ u32 cvtpk_bf16(float lo, float hi) {
  u32 r;
  asm("v_cvt_pk_bf16_f32 %0, %1, %2" : "=v"(r) : "v"(lo), "v"(hi));
  return r;
}

__device__ __forceinline__ float bperm_f(int ibyte, float x) {
  union { float f; int i; } a, b;
  a.f = x;
  b.i = __builtin_amdgcn_ds_bpermute(ibyte, a.i);
  return b.f;
}

// ---------------- K1: 32768-bin histogram of fp32 abs-bits>>16 ----------------
// grid 1024: 512 blocks/tensor, 16384 elem/block; 64.5 KB LDS -> 2 blocks/CU
// (8 waves/CU) for latency hiding; per-block serial chain 4x shorter than grid-256.
__global__ __launch_bounds__(256) void hist_kernel(const float* __restrict__ k,
                                                   const float* __restrict__ v,
                                                   u32* __restrict__ histK,
                                                   u32* __restrict__ histV) {
  __shared__ u32 sh[16384];
  const int tensor = blockIdx.x >> 9;
  const int bid = blockIdx.x & 511;
  const float* src = tensor ? v : k;
  u32* gh = tensor ? histV : histK;
  for (int i = threadIdx.x; i < 16384; i += 256) sh[i] = 0;
  __syncthreads();
  const int per = N_ELEM / 512;  // 16384
  const int base = bid * per;
  for (int i = threadIdx.x; i < per / 4; i += 256) {
    f32x4 x = *(const f32x4*)(src + base + i * 4);
#pragma unroll
    for (int j = 0; j < 4; ++j) {
      union { float f; u32 u; } w; w.f = x[j];
      u32 b = (w.u & 0x7fffffffu) >> 16;
      atomicAdd(&sh[b >> 1], 1u << ((b & 1u) * 16));
    }
  }
  __syncthreads();
  for (int i = threadIdx.x; i < 16384; i += 256) {
    u32 w = sh[i];
    u32 lo = w & 0xffffu, hi = w >> 16;
    if (lo) atomicAdd(&gh[2 * i], lo);
    if (hi) atomicAdd(&gh[2 * i + 1], hi);
  }
}

// ---------------- K2: threshold bin t + tie budget r (LDS-cached scans) -------------
__global__ __launch_bounds__(256) void thresh_kernel(const u32* __restrict__ histK,
                                                     const u32* __restrict__ histV,
                                                     u32* __restrict__ ctrl) {
  const u32* hist = blockIdx.x ? histV : histK;
  u32* c = ctrl + blockIdx.x * 8;
  __shared__ u32 part[256];
  __shared__ u32 bins[128];
  __shared__ u32 sh_chunk, sh_cum;
  u32 s = 0;
  for (int i = 0; i < 128; ++i) s += hist[threadIdx.x * 128 + i];
  part[threadIdx.x] = s;
  __syncthreads();
  if (threadIdx.x == 0) {
    u32 cum = 0;
    int chunk = 255;
    while (chunk > 0 && cum + part[chunk] < KTOP) { cum += part[chunk]; --chunk; }
    sh_chunk = (u32)chunk; sh_cum = cum;
  }
  __syncthreads();
  const u32 chunk = sh_chunk;
  if (threadIdx.x < 128) bins[threadIdx.x] = hist[chunk * 128 + threadIdx.x];
  __syncthreads();
  if (threadIdx.x == 0) {
    u32 cum = sh_cum;
    int b = 127;
    while (b > 0 && cum + bins[b] < KTOP) { cum += bins[b]; --b; }
    c[0] = chunk * 128 + (u32)b;
    c[1] = KTOP - cum;
  }
}

// ---------------- K3: fused candidate gather + per-(h,d) max over bin<t -------------
// grid (256, 2): head h = bx>>3, row-eighth = bx&7 (256 rows/block) -> 2 blocks/CU.
__global__ __launch_bounds__(256) void candmax_kernel(const float* __restrict__ k,
                                                      const float* __restrict__ v,
                                                      u32* __restrict__ ctrl,
                                                      u32* __restrict__ caK, u32* __restrict__ ciK,
                                                      u32* __restrict__ caV, u32* __restrict__ ciV,
                                                      u32* __restrict__ kmax,
                                                      u32* __restrict__ vmax) {
  __shared__ u32 colmax[128];
  const int tensor = blockIdx.y;
  const float* src = tensor ? v : k;
  u32* ca = tensor ? caV : caK;
  u32* ci = tensor ? ciV : ciK;
  u32* cnt = &ctrl[tensor * 8 + 4];
  u32* mbuf = tensor ? vmax : kmax;
  const u32 t = ctrl[tensor * 8 + 0];
  const int h = blockIdx.x >> 3;
  const int q8 = blockIdx.x & 7;
  const int tid = threadIdx.x;
  if (tid < 128) colmax[tid] = 0;
  __syncthreads();
  const int c0 = 4 * (tid & 31);
  u32 mx[4] = {0, 0, 0, 0};
  for (int p = 0; p < 32; ++p) {
    const int s = q8 * 256 + p * 8 + (tid >> 5);
    const u32 idx = ((u32)(h * SEQ + s) << 7) + (u32)c0;
    f32x4 x = *(const f32x4*)(src + idx);
    const bool skipmax = (tensor == 1 && s < 4);
#pragma unroll
    for (int j = 0; j < 4; ++j) {
      union { float f; u32 u; } w; w.f = x[j];
      const u32 ab = w.u & 0x7fffffffu;
      const u32 bin = ab >> 16;
      if (bin == t) {
        u32 slot = atomicAdd(cnt, 1u);
        if (slot < CAND_CAP) { ca[slot] = ab; ci[slot] = idx + j; }
      }
      if (bin < t && !skipmax && ab > mx[j]) mx[j] = ab;
    }
  }
#pragma unroll
  for (int j = 0; j < 4; ++j) atomicMax(&colmax[c0 + j], mx[j]);
  __syncthreads();
  if (tid < 128) atomicMax(&mbuf[h * HD + tid], colmax[tid]);
}

// ---------------- K4: Kr = r-th largest key among candidates (LDS-cached) -----------
__global__ __launch_bounds__(256) void ksel_kernel(u32* __restrict__ ctrl,
                                                   const u32* __restrict__ caK, const u32* __restrict__ ciK,
                                                   const u32* __restrict__ caV, const u32* __restrict__ ciV) {
  __shared__ u64 keys[CAND_CAP];
  const int tensor = blockIdx.y;
  u32* c = ctrl + tensor * 8;
  const u32 r = c[1];
  u32 T = c[4];
  if (T > CAND_CAP) T = CAND_CAP;
  const u32* ca = tensor ? caV : caK;
  const u32* ci = tensor ? ciV : ciK;
  for (u32 j = threadIdx.x; j < T; j += 256)
    keys[j] = (((u64)ca[j]) << 32) | (u32)(~ci[j]);
  __syncthreads();
  for (u32 i = blockIdx.x * 256 + threadIdx.x; i < T; i += 32 * 256) {
    const u64 ki = keys[i];
    u32 cnt = 0;
    for (u32 j = 0; j < T; ++j) cnt += (keys[j] > ki) ? 1u : 0u;
    if (cnt == r - 1) { c[2] = (u32)(ki >> 32); c[3] = (u32)ki; }
  }
}

// ---------------- K5: maxfix (fold bin==t non-outliers) + scale, fused --------------
__global__ __launch_bounds__(256) void maxfix_scale_kernel(const u32* __restrict__ ctrl,
                                                           const u32* __restrict__ caK, const u32* __restrict__ ciK,
                                                           const u32* __restrict__ caV, const u32* __restrict__ ciV,
                                                           u32* __restrict__ kmax, u32* __restrict__ vmax,
                                                           float* __restrict__ kscale, float* __restrict__ vscale) {
  const int tensor = blockIdx.x;
  const u32* c = ctrl + tensor * 8;
  const u64 Kr = (((u64)c[2]) << 32) | c[3];
  u32 T = c[4];
  if (T > CAND_CAP) T = CAND_CAP;
  const u32* ca = tensor ? caV : caK;
  const u32* ci = tensor ? ciV : ciK;
  u32* mbuf = tensor ? vmax : kmax;
  for (u32 i = threadIdx.x; i < T; i += 256) {
    const u32 ab = ca[i], idx = ci[i];
    const u64 key = (((u64)ab) << 32) | (u32)(~idx);
    if (key >= Kr) continue;                              // outlier -> excluded
    if (tensor == 1 && ((idx >> 7) & 2047) < 4) continue; // V sink -> excluded
    atomicMax(&mbuf[(idx >> 18) * HD + (idx & 127)], ab);
  }
  __syncthreads();
  float* sbuf = tensor ? vscale : kscale;
  for (int i = threadIdx.x; i < NH * HD; i += 256) {
    union { u32 u; float f; } a; a.u = mbuf[i];
    sbuf[i] = fmaxf(a.f, 1e-6f) / 7.0f;
  }
}

// ---------------- K6: reconstruct K -> krec (row-major) AND V -> vrecT, one launch ---
// blocks [0,2048): K path (grid-stride). blocks [2048,3072): V transpose path.
__global__ __launch_bounds__(256) void recon_kv_kernel(const float* __restrict__ K,
                                                       const float* __restrict__ V,
                                                       const u32* __restrict__ ctrl,
                                                       const float* __restrict__ kscale,
                                                       const float* __restrict__ vscale,
                                                       u16* __restrict__ krec,
                                                       u16* __restrict__ vrecT) {
  __shared__ u32 ld[64][65];   // [d-pair][s_local], pad 64->65 (V path only)
  const int tid = threadIdx.x;
  if (blockIdx.x < 2048) {
    const u32 t = ctrl[0];
    const u64 Kr = (((u64)ctrl[2]) << 32) | ctrl[3];
    const int stride = 2048 * 256;
    for (int i = blockIdx.x * 256 + tid; i < N_ELEM / 4; i += stride) {
      const u32 e = (u32)i * 4;
      const u32 d0 = e & 127, h = e >> 18;
      f32x4 x = *(const f32x4*)(K + e);
      f32x4 sc = *(const f32x4*)(kscale + h * HD + d0);
      u16 y[4];
#pragma unroll
      for (int j = 0; j < 4; ++j) y[j] = f2bf(dqf(x[j], t, Kr, e + j, false, sc[j]));
      *(u32*)(krec + e) = ((u32)y[0]) | (((u32)y[1]) << 16);
      *(u32*)(krec + e + 2) = ((u32)y[2]) | (((u32)y[3]) << 16);
    }
  } else {
    const int b = blockIdx.x - 2048;
    const u32 t = ctrl[8];
    const u64 Kr = (((u64)ctrl[10]) << 32) | ctrl[11];
    const int h = b >> 5, sb = b & 31;
    const int d0 = 4 * (tid & 31);
    f32x4 sc = *(const f32x4*)(vscale + h * HD + d0);
#pragma unroll
    for (int p = 0; p < 8; ++p) {
      const int sl = p * 8 + (tid >> 5);
      const int tok = sb * 64 + sl;
      const bool sink = tok < 4;
      const u32 idx = ((u32)(h * SEQ + tok) << 7) + (u32)d0;
      f32x4 x = *(const f32x4*)(V + idx);
      u16 y[4];
#pragma unroll
      for (int j = 0; j < 4; ++j) y[j] = f2bf(dqf(x[j], t, Kr, idx + j, sink, sc[j]));
      ld[(d0 >> 1)][sl] = ((u32)y[0]) | (((u32)y[1]) << 16);
      ld[(d0 >> 1) + 1][sl] = ((u32)y[2]) | (((u32)y[3]) << 16);
    }
    __syncthreads();
    const int d = tid >> 1, so = (tid & 1) * 32, e = d & 1;
    u16* outp = vrecT + (size_t)(h * 32 + sb) * 8192 + d * 64 + so;
#pragma unroll
    for (int i = 0; i < 4; ++i) {
      short8 y;
#pragma unroll
      for (int m = 0; m < 8; ++m) {
        const u32 w2 = ld[d >> 1][so + i * 8 + m];
        y[m] = (short)(u16)(w2 >> (16 * e));
      }
      *(short8*)(outp + i * 8) = y;
    }
  }
}

// ---------------- K8: flash attention, swapped-QK, 8-wave blocks (R4 + defer-max) ---
// Block = head h x pair a: q-tiles {a, 31-a}; 512 threads: waves 0-3 own subtile A,
// waves 4-7 own subtile B; 2 blocks/CU = 16 waves/CU.
// QK^T as mfma(K, Q): lane owns ONE q-row (l16); bit-shuffled K rows make the lane's
// 16 scores exactly the PV A-fragment after v_cvt_pk_bf16_f32 (no P LDS round-trip).
// XCD swizzle: 4 heads per XCD -> per-XCD K/V working set = 4 MB = L2 size.
// T13 defer-max: skip O-rescale while tile max grows < 8 (exp2 domain, P <= 256).
#define SC_QK 0.12751743f   // log2(e)/sqrt(128): exp2-domain softmax
#define NEGS -30000.0f

__global__ __launch_bounds__(512, 4) void flash_pre(const float* __restrict__ Q,
                                                    const u16* __restrict__ krec,
                                                    const u16* __restrict__ vrecT,
                                                    float* __restrict__ Out) {
  __shared__ u16 ks[64][132];     // K tile (permuted token rows x channel)
  __shared__ u16 vt[128][68];     // V^T tile (channel x token)

  // XCD swizzle: xcd = b&7 serves heads {xcd, xcd+8, xcd+16, xcd+24}
  const int b = blockIdx.x;       // 512 = 32 heads x 16 pairs
  const int h = (b & 7) + 8 * ((b >> 3) >> 4);
  const int pa = (b >> 3) & 15;
  const int RA = pa << 6;          // q-tile A row base (0..960)
  const int RB = (31 - pa) << 6;   // q-tile B row base (1024..1984)
  const int tid = threadIdx.x;
  const int w = tid >> 6, lane = tid & 63;
  const int ww = w & 3;            // wave index within subtile group
  const int R = (w >> 2) ? RB : RA;  // this wave's subtile row base
  const int l16 = lane & 15, quad = lane >> 4;
  const int qrow16 = ww * 16 + l16;  // this lane's q-row within the 64-row subtile

  int idxR[4];                     // bpermute byte-idx: same-quad lane with l16 = quad*4+r
#pragma unroll
  for (int r = 0; r < 4; ++r) idxR[r] = ((lane & 48) | (quad * 4 + r)) << 2;

  // Q fragment for this wave's subtile (B-operand: col = q = l16)
  short8 qf[4];
  {
    const float* qp = Q + ((size_t)(h * SEQ + R + ww * 16 + l16)) * HD + quad * 8;
#pragma unroll
    for (int c = 0; c < 4; ++c) {
      f32x4 a = *(const f32x4*)(qp + c * 32);
      f32x4 bb = *(const f32x4*)(qp + c * 32 + 4);
      union { u32 u[4]; short8 v; } t;
      t.u[0] = cvtpk_bf16(a[0], a[1]);
      t.u[1] = cvtpk_bf16(a[2], a[3]);
      t.u[2] = cvtpk_bf16(bb[0], bb[1]);
      t.u[3] = cvtpk_bf16(bb[2], bb[3]);
      qf[c] = t.v;
    }
  }

  f32x4 o[8];
#pragma unroll
  for (int i = 0; i < 8; ++i) o[i] = (f32x4){0.f, 0.f, 0.f, 0.f};
  float mrow = NEGS, lrow = 0.f;

  // staging thread mapping (512 threads) + prefetch registers
  const int krow = tid >> 3, kqo = (tid & 7) * 16;   // K: 64 rows x 256B, 8 thr/row
  // token->LDS-row bit shuffle: x = [t5 t2 | t4 t3 | t1 t0]
  const int krp = (krow & 35) | (((krow >> 2) & 1) << 4) |
                  (((krow >> 4) & 1) << 3) | (((krow >> 3) & 1) << 2);
  // V^T: 128 rows x 64 u16, 4 thr/row; thread covers {vco, vco+32}, vco in {0,8,16,24}
  const int vd = tid >> 2, vco = (tid & 3) * 8;
  const u16* kbase = krec + ((size_t)h * SEQ + krow) * HD + kqo;
  const u16* vbase = vrecT + (size_t)h * 32 * 8192 + vd * 64 + vco;
  short8 kr[2], vr, vr2;
  kr[0] = *(const short8*)(kbase);
  kr[1] = *(const short8*)(kbase + 8);
  vr = *(const short8*)(vbase);
  vr2 = *(const short8*)(vbase + 32);

  const int ktiles = (RB >> 6) + 1;   // 17..32
  for (int kt = 0; kt < ktiles; ++kt) {
    const int kb = kt << 6;
    __syncthreads();                  // previous compute done with LDS
    *(short8*)(&ks[krp][kqo]) = kr[0];
    *(short8*)(&ks[krp][kqo + 8]) = kr[1];
    *(short8*)(&vt[vd][vco]) = vr;
    *(short8*)(&vt[vd][vco + 32]) = vr2;
    __syncthreads();
    if (kt + 1 < ktiles) {            // prefetch next tile under this tile's compute
      const u16* kp = kbase + (size_t)(kt + 1) * 64 * HD;
      const u16* vp = vbase + (size_t)(kt + 1) * 8192;
      kr[0] = *(const short8*)(kp);
      kr[1] = *(const short8*)(kp + 8);
      vr = *(const short8*)(vp);
      vr2 = *(const short8*)(vp + 32);
    }
    if (kb <= R) {
      // S^T = K Q^T: A = K frags from LDS, B = Q regs
      f32x4 s[4];
      __builtin_amdgcn_s_setprio(1);
#pragma unroll
      for (int ni = 0; ni < 4; ++ni) {
        f32x4 acc = (f32x4){0.f, 0.f, 0.f, 0.f};
#pragma unroll
        for (int c = 0; c < 4; ++c) {
          short8 kf = *(const short8*)(&ks[ni * 16 + l16][c * 32 + quad * 8]);
          acc = __builtin_amdgcn_mfma_f32_16x16x32_bf16(kf, qf[c], acc, 0, 0, 0);
        }
        s[ni] = acc;
      }
      __builtin_amdgcn_s_setprio(0);

      // softmax with defer-max; token of s[ni][r] = (ni>>1)*32 + quad*8 + (ni&1)*4 + r
      const bool diag = (kb == R);
#pragma unroll
      for (int ni = 0; ni < 4; ++ni)
#pragma unroll
        for (int r = 0; r < 4; ++r) {
          float sv = s[ni][r] * SC_QK;
          const int tokl = ((ni >> 1) << 5) | (quad << 3) | ((ni & 1) << 2) | r;
          if (diag && tokl > qrow16) sv = NEGS;
          s[ni][r] = sv;
        }
      float m01 = fmaxf(fmaxf(fmaxf(s[0][0], s[0][1]), fmaxf(s[0][2], s[0][3])),
                        fmaxf(fmaxf(s[1][0], s[1][1]), fmaxf(s[1][2], s[1][3])));
      float m23 = fmaxf(fmaxf(fmaxf(s[2][0], s[2][1]), fmaxf(s[2][2], s[2][3])),
                        fmaxf(fmaxf(s[3][0], s[3][1]), fmaxf(s[3][2], s[3][3])));
      float mx = fmaxf(m01, m23);
      mx = fmaxf(mx, __shfl_xor(mx, 16));
      mx = fmaxf(mx, __shfl_xor(mx, 32));
      const bool skip = (__ballot(mx <= mrow + 8.0f) == ~0ull);
      float al = 1.0f;
      if (!skip) {
        const float mnew = fmaxf(mrow, mx);
        al = exp2f(mrow - mnew);
        mrow = mnew;
      }
      float sum = 0.f;
#pragma unroll
      for (int ni = 0; ni < 4; ++ni)
#pragma unroll
        for (int r = 0; r < 4; ++r) {
          const float p = exp2f(s[ni][r] - mrow);
          s[ni][r] = p;
          sum += p;
        }
      sum += __shfl_xor(sum, 16);
      sum += __shfl_xor(sum, 32);
      lrow = skip ? (lrow + sum) : (lrow * al + sum);
      // pack P to bf16 pairs: pk[4*kc + {0..3}] = A-frag dwords for PV k-chunk kc
      u32 pk[8];
#pragma unroll
      for (int ni = 0; ni < 4; ++ni) {
        pk[ni * 2] = cvtpk_bf16(s[ni][0], s[ni][1]);
        pk[ni * 2 + 1] = cvtpk_bf16(s[ni][2], s[ni][3]);
      }
      if (!skip) {
        f32x4 av;   // alpha redistributed to output-row layout
#pragma unroll
        for (int r = 0; r < 4; ++r) av[r] = bperm_f(idxR[r], al);
#pragma unroll
        for (int i = 0; i < 8; ++i) o[i] *= av;
      }

      // O += P V  (P A-frags are lane-local registers; V frags from LDS)
      __builtin_amdgcn_s_setprio(1);
#pragma unroll
      for (int kc = 0; kc < 2; ++kc) {
        union { u32 u[4]; short8 v; } au;
#pragma unroll
        for (int t = 0; t < 4; ++t) au.u[t] = pk[kc * 4 + t];
        const short8 af = au.v;
#pragma unroll
        for (int ds = 0; ds < 8; ++ds) {
          short8 vf = *(const short8*)(&vt[ds * 16 + l16][kc * 32 + quad * 8]);
          o[ds] = __builtin_amdgcn_mfma_f32_16x16x32_bf16(af, vf, o[ds], 0, 0, 0);
        }
      }
      __builtin_amdgcn_s_setprio(0);
    }
  }

  // epilogue
  {
    float linv[4];
#pragma unroll
    for (int r = 0; r < 4; ++r) linv[r] = 1.0f / bperm_f(idxR[r], lrow);
#pragma unroll
    for (int r = 0; r < 4; ++r) {
      const int qr = R + ww * 16 + quad * 4 + r;
      float* op = Out + ((size_t)(h * SEQ + qr)) * HD + l16;
#pragma unroll
      for (int ds = 0; ds < 8; ++ds) op[ds * 16] = o[ds][r] * linv[r];
    }
  }
}

// ---------------- fallback flash (round-3/4 passing version, inline dequant) --------
__global__ __launch_bounds__(256, 2) void flash_fb(const float* __restrict__ Q,
                                                   const float* __restrict__ K,
                                                   const float* __restrict__ V,
                                                   const u32* __restrict__ ctrl,
                                                   const float* __restrict__ kscale,
                                                   const float* __restrict__ vscale,
                                                   float* __restrict__ Out) {
  __shared__ u16 ks[64][136];
  __shared__ u16 vt[128][72];
  __shared__ u16 pl[4][16][72];
  const int blk = blockIdx.x;
  const int h = blk >> 5;
  const int qt = 31 - (blk & 31);
  const int qb = qt << 6;
  const int tid = threadIdx.x;
  const int w = tid >> 6, lane = tid & 63;
  const int l16 = lane & 15, quad = lane >> 4;
  const float SM_SCALE = 0.08838834764831843f;
  const float NEG = -30000.0f;
  const u32 tK = ctrl[0];
  const u64 KrK = (((u64)ctrl[2]) << 32) | ctrl[3];
  const u32 tV = ctrl[8];
  const u64 KrV = (((u64)ctrl[10]) << 32) | ctrl[11];
  const int cch = (tid & 15) * 8;
  float ksc[8], vsc[8];
#pragma unroll
  for (int j = 0; j < 8; ++j) {
    ksc[j] = kscale[h * HD + cch + j];
    vsc[j] = vscale[h * HD + cch + j];
  }
  short8 qf[4];
  {
    const float* qp = Q + ((size_t)(h * SEQ + qb + w * 16 + l16)) * HD + quad * 8;
#pragma unroll
    for (int c = 0; c < 4; ++c) {
      f32x4 a = *(const f32x4*)(qp + c * 32);
      f32x4 b = *(const f32x4*)(qp + c * 32 + 4);
#pragma unroll
      for (int j = 0; j < 4; ++j) {
        qf[c][j] = (short)f2bf(a[j]);
        qf[c][4 + j] = (short)f2bf(b[j]);
      }
    }
  }
  f32x4 o[8];
#pragma unroll
  for (int i = 0; i < 8; ++i) o[i] = (f32x4){0.f, 0.f, 0.f, 0.f};
  float mrow[4], lrow[4];
#pragma unroll
  for (int r = 0; r < 4; ++r) { mrow[r] = NEG; lrow[r] = 0.f; }
  const int ktiles = qt + 1;
  for (int kt = 0; kt < ktiles; ++kt) {
    const int kb = kt << 6;
    __syncthreads();
    {
      const int r0 = tid >> 4;
      const float* kp = K + (size_t)(h * SEQ + kb) * HD;
#pragma unroll
      for (int i = 0; i < 4; ++i) {
        const int row = r0 + i * 16;
        f32x4 x0 = *(const f32x4*)(kp + (size_t)row * HD + cch);
        f32x4 x1 = *(const f32x4*)(kp + (size_t)row * HD + cch + 4);
        const u32 bidx = ((u32)(h * SEQ + kb + row) << 7) + (u32)cch;
        short8 yv;
#pragma unroll
        for (int j = 0; j < 4; ++j) {
          yv[j]     = (short)f2bf(dqf(x0[j], tK, KrK, bidx + j,     false, ksc[j]));
          yv[4 + j] = (short)f2bf(dqf(x1[j], tK, KrK, bidx + 4 + j, false, ksc[4 + j]));
        }
        *(short8*)(&ks[row][cch]) = yv;
      }
    }
    {
      const float* vp = V + (size_t)(h * SEQ + kb) * HD;
#pragma unroll
      for (int i = 0; i < 4; ++i) {
        const int tchunk = tid + i * 256;
        const int s = tchunk >> 4;
        const int tok = kb + s;
        const bool sink = tok < 4;
        f32x4 x0 = *(const f32x4*)(vp + (size_t)s * HD + cch);
        f32x4 x1 = *(const f32x4*)(vp + (size_t)s * HD + cch + 4);
        const u32 bidx = ((u32)(h * SEQ + tok) << 7) + (u32)cch;
#pragma unroll
        for (int j = 0; j < 4; ++j) {
          vt[cch + j][s]     = f2bf(dqf(x0[j], tV, KrV, bidx + j,     sink, vsc[j]));
          vt[cch + 4 + j][s] = f2bf(dqf(x1[j], tV, KrV, bidx + 4 + j, sink, vsc[4 + j]));
        }
      }
    }
    __syncthreads();
    f32x4 sa[4];
#pragma unroll
    for (int ni = 0; ni < 4; ++ni) {
      f32x4 acc = (f32x4){0.f, 0.f, 0.f, 0.f};
#pragma unroll
      for (int c = 0; c < 4; ++c) {
        short8 kf = *(const short8*)(&ks[ni * 16 + l16][c * 32 + quad * 8]);
        acc = __builtin_amdgcn_mfma_f32_16x16x32_bf16(qf[c], kf, acc, 0, 0, 0);
      }
      sa[ni] = acc;
    }
    const bool diag = (kb == qb);
#pragma unroll
    for (int ni = 0; ni < 4; ++ni)
#pragma unroll
      for (int r = 0; r < 4; ++r) {
        float sv = sa[ni][r] * SM_SCALE;
        if (diag) {
          const int qr = w * 16 + quad * 4 + r;
          const int kc = ni * 16 + l16;
          if (kc > qr) sv = NEG;
        }
        sa[ni][r] = sv;
      }
    float alpha[4];
#pragma unroll
    for (int r = 0; r < 4; ++r) {
      float mx = fmaxf(fmaxf(sa[0][r], sa[1][r]), fmaxf(sa[2][r], sa[3][r]));
      mx = fmaxf(mx, __shfl_xor(mx, 1));
      mx = fmaxf(mx, __shfl_xor(mx, 2));
      mx = fmaxf(mx, __shfl_xor(mx, 4));
      mx = fmaxf(mx, __shfl_xor(mx, 8));
      const float mn = fmaxf(mrow[r], mx);
      alpha[r] = __expf(mrow[r] - mn);
      mrow[r] = mn;
      float sum = 0.f;
#pragma unroll
      for (int ni = 0; ni < 4; ++ni) {
        const float p = __expf(sa[ni][r] - mn);
        sa[ni][r] = p;
        sum += p;
      }
      sum += __shfl_xor(sum, 1);
      sum += __shfl_xor(sum, 2);
      sum += __shfl_xor(sum, 4);
      sum += __shfl_xor(sum, 8);
      lrow[r] = lrow[r] * alpha[r] + sum;
    }
#pragma unroll
    for (int ni = 0; ni < 4; ++ni)
#pragma unroll
      for (int r = 0; r < 4; ++r)
        pl[w][quad * 4 + r][ni * 16 + l16] = f2bf(sa[ni][r]);
    __syncthreads();
#pragma unroll
    for (int i = 0; i < 8; ++i)
#pragma unroll
      for (int r = 0; r < 4; ++r) o[i][r] *= alpha[r];
#pragma unroll
    for (int kc = 0; kc < 2; ++kc) {
      short8 af = *(const short8*)(&pl[w][l16][kc * 32 + quad * 8]);
#pragma unroll
      for (int ds = 0; ds < 8; ++ds) {
        short8 vf = *(const short8*)(&vt[ds * 16 + l16][kc * 32 + quad * 8]);
        o[ds] = __builtin_amdgcn_mfma_f32_16x16x32_bf16(af, vf, o[ds], 0, 0, 0);
      }
    }
  }
#pragma unroll
  for (int r = 0; r < 4; ++r) {
    const float inv = 1.0f / lrow[r];
    const int qr = qb + w * 16 + quad * 4 + r;
    float* op = Out + ((size_t)(h * SEQ + qr)) * HD + l16;
#pragma unroll
    for (int ds = 0; ds < 8; ++ds) op[ds * 16] = o[ds][r] * inv;
  }
}

// ---------------- launcher ----------------
extern "C" void kernel_launch(void* const* d_in, const int* in_sizes, int n_in,
                              void* d_out, int out_size, void* d_ws, size_t ws_size,
                              hipStream_t stream) {
  const float* q = (const float*)d_in[0];
  const float* k = (const float*)d_in[1];
  const float* v = (const float*)d_in[2];
  float* out = (float*)d_out;
  char* ws = (char*)d_ws;

  u32* ctrl    = (u32*)ws;                               // 256 B
  u32* histK   = (u32*)(ws + 256);                       // 128 KB
  u32* histV   = (u32*)(ws + 256 + 131072);              // 128 KB
  u32* kmax    = (u32*)(ws + 262400);                    // 16 KB
  u32* vmax    = (u32*)(ws + 278784);                    // 16 KB
  const size_t ZERO_BYTES = 295168;                      // ctrl+hists+maxes
  float* kscale = (float*)(ws + 295168);                 // 16 KB
  float* vscale = (float*)(ws + 311552);                 // 16 KB
  u32* caK = (u32*)(ws + 327936);                        // 4x32 KB
  u32* ciK = caK + CAND_CAP;
  u32* caV = ciK + CAND_CAP;
  u32* ciV = caV + CAND_CAP;
  u16* krec  = (u16*)(ws + 458752);                      // 16 MB
  u16* vrecT = (u16*)(ws + 458752 + 16777216);           // 16 MB
  const size_t NEED = 458752 + 2ull * 16777216;

  hipMemsetAsync(ws, 0, ZERO_BYTES, stream);
  hist_kernel<<<1024, 256, 0, stream>>>(k, v, histK, histV);
  thresh_kernel<<<2, 256, 0, stream>>>(histK, histV, ctrl);
  candmax_kernel<<<dim3(256, 2), 256, 0, stream>>>(k, v, ctrl, caK, ciK, caV, ciV, kmax, vmax);
  ksel_kernel<<<dim3(32, 2), 256, 0, stream>>>(ctrl, caK, ciK, caV, ciV);
  maxfix_scale_kernel<<<2, 256, 0, stream>>>(ctrl, caK, ciK, caV, ciV, kmax, vmax, kscale, vscale);
  if (ws_size >= NEED) {
    recon_kv_kernel<<<3072, 256, 0, stream>>>(k, v, ctrl, kscale, vscale, krec, vrecT);
    flash_pre<<<512, 512, 0, stream>>>(q, krec, vrecT, out);
  } else {
    flash_fb<<<32 * 32, 256, 0, stream>>>(q, k, v, ctrl, kscale, vscale, out);
  }
}

// Round 10
// 328.789 us; speedup vs baseline: 1.2530x; 1.0999x over previous
//
#include <hip/hip_runtime.h>

typedef unsigned short u16;
typedef unsigned int u32;
typedef unsigned long long u64;
typedef __attribute__((ext_vector_type(8))) short short8;
typedef __attribute__((ext_vector_type(4))) float f32x4;

#define N_ELEM 8388608
#define NH 32
#define SEQ 2048
#define HD 128
#define KTOP 32768u
#define CAND_CAP 8192u

__device__ __forceinline__ u16 f2bf(float f) {
  union { float f; u32 u; } v; v.f = f;
  u32 r = v.u + 0x7fffu + ((v.u >> 16) & 1u);
  return (u16)(r >> 16);
}

// fp32 quant-dequant, exact reference semantics; keeps outliers & sinks verbatim
__device__ __forceinline__ float dqf(float x, u32 t, u64 Kr, u32 idx, bool sink, float scale) {
  union { float f; u32 u; } w; w.f = x;
  const u32 ab = w.u & 0x7fffffffu;
  const u32 bin = ab >> 16;
  const bool keep = sink || (bin > t) ||
                    (bin == t && ((((u64)ab) << 32) | (u32)(~idx)) >= Kr);
  if (keep) return x;
  float q = rintf(x / scale);            // round-half-even == jnp.round
  q = fminf(fmaxf(q, -8.0f), 7.0f);
  return q * scale;
}

// packed fp32->bf16 RNE (identical rounding to f2bf); no builtin on gfx950
__device__ __forceinline__ u32 cvtpk_bf16(float lo, float hi) {
  u32 r;
  asm("v_cvt_pk_bf16_f32 %0, %1, %2" : "=v"(r) : "v"(lo), "v"(hi));
  return r;
}

__device__ __forceinline__ float bperm_f(int ibyte, float x) {
  union { float f; int i; } a, b;
  a.f = x;
  b.i = __builtin_amdgcn_ds_bpermute(ibyte, a.i);
  return b.f;
}

// ---------------- K1: 32768-bin histogram of fp32 abs-bits>>16 ----------------
// 512 thr x 512 blocks (256/tensor, 32768 elem/block): serial depth 80 iters
// (32 zero + 16 load + 32 merge), 64 KB LDS -> 2 blocks/CU = 16 waves/CU.
// Per-block bin count <= 32768 fits the packed u16 counters.
__global__ __launch_bounds__(512) void hist_kernel(const float* __restrict__ k,
                                                   const float* __restrict__ v,
                                                   u32* __restrict__ histK,
                                                   u32* __restrict__ histV) {
  __shared__ u32 sh[16384];
  const int tensor = blockIdx.x >> 8;
  const int bid = blockIdx.x & 255;
  const float* src = tensor ? v : k;
  u32* gh = tensor ? histV : histK;
  for (int i = threadIdx.x; i < 16384; i += 512) sh[i] = 0;
  __syncthreads();
  const int per = N_ELEM / 256;  // 32768
  const int base = bid * per;
  for (int i = threadIdx.x; i < per / 4; i += 512) {
    f32x4 x = *(const f32x4*)(src + base + i * 4);
#pragma unroll
    for (int j = 0; j < 4; ++j) {
      union { float f; u32 u; } w; w.f = x[j];
      u32 b = (w.u & 0x7fffffffu) >> 16;
      atomicAdd(&sh[b >> 1], 1u << ((b & 1u) * 16));
    }
  }
  __syncthreads();
  for (int i = threadIdx.x; i < 16384; i += 512) {
    u32 w = sh[i];
    u32 lo = w & 0xffffu, hi = w >> 16;
    if (lo) atomicAdd(&gh[2 * i], lo);
    if (hi) atomicAdd(&gh[2 * i + 1], hi);
  }
}

// ---------------- K2: threshold bin t + tie budget r (LDS-cached scans) -------------
__global__ __launch_bounds__(256) void thresh_kernel(const u32* __restrict__ histK,
                                                     const u32* __restrict__ histV,
                                                     u32* __restrict__ ctrl) {
  const u32* hist = blockIdx.x ? histV : histK;
  u32* c = ctrl + blockIdx.x * 8;
  __shared__ u32 part[256];
  __shared__ u32 bins[128];
  __shared__ u32 sh_chunk, sh_cum;
  u32 s = 0;
  for (int i = 0; i < 128; ++i) s += hist[threadIdx.x * 128 + i];
  part[threadIdx.x] = s;
  __syncthreads();
  if (threadIdx.x == 0) {
    u32 cum = 0;
    int chunk = 255;
    while (chunk > 0 && cum + part[chunk] < KTOP) { cum += part[chunk]; --chunk; }
    sh_chunk = (u32)chunk; sh_cum = cum;
  }
  __syncthreads();
  const u32 chunk = sh_chunk;
  if (threadIdx.x < 128) bins[threadIdx.x] = hist[chunk * 128 + threadIdx.x];
  __syncthreads();
  if (threadIdx.x == 0) {
    u32 cum = sh_cum;
    int b = 127;
    while (b > 0 && cum + bins[b] < KTOP) { cum += bins[b]; --b; }
    c[0] = chunk * 128 + (u32)b;
    c[1] = KTOP - cum;
  }
}

// ---------------- K3: fused candidate gather + per-(h,d) max over bin<t -------------
// grid (256, 2) x 512 thr: 256 rows/block, 16 rows in flight -> 16-iter serial chain;
// 2 blocks/CU = 16 waves/CU.
__global__ __launch_bounds__(512) void candmax_kernel(const float* __restrict__ k,
                                                      const float* __restrict__ v,
                                                      u32* __restrict__ ctrl,
                                                      u32* __restrict__ caK, u32* __restrict__ ciK,
                                                      u32* __restrict__ caV, u32* __restrict__ ciV,
                                                      u32* __restrict__ kmax,
                                                      u32* __restrict__ vmax) {
  __shared__ u32 colmax[128];
  const int tensor = blockIdx.y;
  const float* src = tensor ? v : k;
  u32* ca = tensor ? caV : caK;
  u32* ci = tensor ? ciV : ciK;
  u32* cnt = &ctrl[tensor * 8 + 4];
  u32* mbuf = tensor ? vmax : kmax;
  const u32 t = ctrl[tensor * 8 + 0];
  const int h = blockIdx.x >> 3;
  const int q8 = blockIdx.x & 7;
  const int tid = threadIdx.x;
  if (tid < 128) colmax[tid] = 0;
  __syncthreads();
  const int c0 = 4 * (tid & 31);
  u32 mx[4] = {0, 0, 0, 0};
  for (int p = 0; p < 16; ++p) {
    const int s = q8 * 256 + p * 16 + (tid >> 5);
    const u32 idx = ((u32)(h * SEQ + s) << 7) + (u32)c0;
    f32x4 x = *(const f32x4*)(src + idx);
    const bool skipmax = (tensor == 1 && s < 4);
#pragma unroll
    for (int j = 0; j < 4; ++j) {
      union { float f; u32 u; } w; w.f = x[j];
      const u32 ab = w.u & 0x7fffffffu;
      const u32 bin = ab >> 16;
      if (bin == t) {
        u32 slot = atomicAdd(cnt, 1u);
        if (slot < CAND_CAP) { ca[slot] = ab; ci[slot] = idx + j; }
      }
      if (bin < t && !skipmax && ab > mx[j]) mx[j] = ab;
    }
  }
#pragma unroll
  for (int j = 0; j < 4; ++j) atomicMax(&colmax[c0 + j], mx[j]);
  __syncthreads();
  if (tid < 128) atomicMax(&mbuf[h * HD + tid], colmax[tid]);
}

// ---------------- K4: Kr = r-th largest key among candidates (LDS-cached) -----------
__global__ __launch_bounds__(256) void ksel_kernel(u32* __restrict__ ctrl,
                                                   const u32* __restrict__ caK, const u32* __restrict__ ciK,
                                                   const u32* __restrict__ caV, const u32* __restrict__ ciV) {
  __shared__ u64 keys[CAND_CAP];
  const int tensor = blockIdx.y;
  u32* c = ctrl + tensor * 8;
  const u32 r = c[1];
  u32 T = c[4];
  if (T > CAND_CAP) T = CAND_CAP;
  const u32* ca = tensor ? caV : caK;
  const u32* ci = tensor ? ciV : ciK;
  for (u32 j = threadIdx.x; j < T; j += 256)
    keys[j] = (((u64)ca[j]) << 32) | (u32)(~ci[j]);
  __syncthreads();
  for (u32 i = blockIdx.x * 256 + threadIdx.x; i < T; i += 32 * 256) {
    const u64 ki = keys[i];
    u32 cnt = 0;
    for (u32 j = 0; j < T; ++j) cnt += (keys[j] > ki) ? 1u : 0u;
    if (cnt == r - 1) { c[2] = (u32)(ki >> 32); c[3] = (u32)ki; }
  }
}

// ---------------- K5: maxfix (fold bin==t non-outliers) + scale, fused --------------
__global__ __launch_bounds__(256) void maxfix_scale_kernel(const u32* __restrict__ ctrl,
                                                           const u32* __restrict__ caK, const u32* __restrict__ ciK,
                                                           const u32* __restrict__ caV, const u32* __restrict__ ciV,
                                                           u32* __restrict__ kmax, u32* __restrict__ vmax,
                                                           float* __restrict__ kscale, float* __restrict__ vscale) {
  const int tensor = blockIdx.x;
  const u32* c = ctrl + tensor * 8;
  const u64 Kr = (((u64)c[2]) << 32) | c[3];
  u32 T = c[4];
  if (T > CAND_CAP) T = CAND_CAP;
  const u32* ca = tensor ? caV : caK;
  const u32* ci = tensor ? ciV : ciK;
  u32* mbuf = tensor ? vmax : kmax;
  for (u32 i = threadIdx.x; i < T; i += 256) {
    const u32 ab = ca[i], idx = ci[i];
    const u64 key = (((u64)ab) << 32) | (u32)(~idx);
    if (key >= Kr) continue;                              // outlier -> excluded
    if (tensor == 1 && ((idx >> 7) & 2047) < 4) continue; // V sink -> excluded
    atomicMax(&mbuf[(idx >> 18) * HD + (idx & 127)], ab);
  }
  __syncthreads();
  float* sbuf = tensor ? vscale : kscale;
  for (int i = threadIdx.x; i < NH * HD; i += 256) {
    union { u32 u; float f; } a; a.u = mbuf[i];
    sbuf[i] = fmaxf(a.f, 1e-6f) / 7.0f;
  }
}

// ---------------- K6: reconstruct K -> krec (row-major) AND V -> vrecT, one launch ---
// blocks [0,2048): K path (grid-stride). blocks [2048,3072): V transpose path.
__global__ __launch_bounds__(256) void recon_kv_kernel(const float* __restrict__ K,
                                                       const float* __restrict__ V,
                                                       const u32* __restrict__ ctrl,
                                                       const float* __restrict__ kscale,
                                                       const float* __restrict__ vscale,
                                                       u16* __restrict__ krec,
                                                       u16* __restrict__ vrecT) {
  __shared__ u32 ld[64][65];   // [d-pair][s_local], pad 64->65 (V path only)
  const int tid = threadIdx.x;
  if (blockIdx.x < 2048) {
    const u32 t = ctrl[0];
    const u64 Kr = (((u64)ctrl[2]) << 32) | ctrl[3];
    const int stride = 2048 * 256;
    for (int i = blockIdx.x * 256 + tid; i < N_ELEM / 4; i += stride) {
      const u32 e = (u32)i * 4;
      const u32 d0 = e & 127, h = e >> 18;
      f32x4 x = *(const f32x4*)(K + e);
      f32x4 sc = *(const f32x4*)(kscale + h * HD + d0);
      u16 y[4];
#pragma unroll
      for (int j = 0; j < 4; ++j) y[j] = f2bf(dqf(x[j], t, Kr, e + j, false, sc[j]));
      *(u32*)(krec + e) = ((u32)y[0]) | (((u32)y[1]) << 16);
      *(u32*)(krec + e + 2) = ((u32)y[2]) | (((u32)y[3]) << 16);
    }
  } else {
    const int b = blockIdx.x - 2048;
    const u32 t = ctrl[8];
    const u64 Kr = (((u64)ctrl[10]) << 32) | ctrl[11];
    const int h = b >> 5, sb = b & 31;
    const int d0 = 4 * (tid & 31);
    f32x4 sc = *(const f32x4*)(vscale + h * HD + d0);
#pragma unroll
    for (int p = 0; p < 8; ++p) {
      const int sl = p * 8 + (tid >> 5);
      const int tok = sb * 64 + sl;
      const bool sink = tok < 4;
      const u32 idx = ((u32)(h * SEQ + tok) << 7) + (u32)d0;
      f32x4 x = *(const f32x4*)(V + idx);
      u16 y[4];
#pragma unroll
      for (int j = 0; j < 4; ++j) y[j] = f2bf(dqf(x[j], t, Kr, idx + j, sink, sc[j]));
      ld[(d0 >> 1)][sl] = ((u32)y[0]) | (((u32)y[1]) << 16);
      ld[(d0 >> 1) + 1][sl] = ((u32)y[2]) | (((u32)y[3]) << 16);
    }
    __syncthreads();
    const int d = tid >> 1, so = (tid & 1) * 32, e = d & 1;
    u16* outp = vrecT + (size_t)(h * 32 + sb) * 8192 + d * 64 + so;
#pragma unroll
    for (int i = 0; i < 4; ++i) {
      short8 y;
#pragma unroll
      for (int m = 0; m < 8; ++m) {
        const u32 w2 = ld[d >> 1][so + i * 8 + m];
        y[m] = (short)(u16)(w2 >> (16 * e));
      }
      *(short8*)(outp + i * 8) = y;
    }
  }
}

// ---------------- K8: flash attention, swapped-QK, 8-wave blocks (R4 + defer-max) ---
// Block = head h x pair a: q-tiles {a, 31-a}; 512 threads: waves 0-3 own subtile A,
// waves 4-7 own subtile B; 2 blocks/CU = 16 waves/CU.
// QK^T as mfma(K, Q): lane owns ONE q-row (l16); bit-shuffled K rows make the lane's
// 16 scores exactly the PV A-fragment after v_cvt_pk_bf16_f32 (no P LDS round-trip).
// XCD swizzle: 4 heads per XCD -> per-XCD K/V working set = 4 MB = L2 size.
// T13 defer-max: skip O-rescale while tile max grows < 8 (exp2 domain, P <= 256).
#define SC_QK 0.12751743f   // log2(e)/sqrt(128): exp2-domain softmax
#define NEGS -30000.0f

__global__ __launch_bounds__(512, 4) void flash_pre(const float* __restrict__ Q,
                                                    const u16* __restrict__ krec,
                                                    const u16* __restrict__ vrecT,
                                                    float* __restrict__ Out) {
  __shared__ u16 ks[64][132];     // K tile (permuted token rows x channel)
  __shared__ u16 vt[128][68];     // V^T tile (channel x token)

  // XCD swizzle: xcd = b&7 serves heads {xcd, xcd+8, xcd+16, xcd+24}
  const int b = blockIdx.x;       // 512 = 32 heads x 16 pairs
  const int h = (b & 7) + 8 * ((b >> 3) >> 4);
  const int pa = (b >> 3) & 15;
  const int RA = pa << 6;          // q-tile A row base (0..960)
  const int RB = (31 - pa) << 6;   // q-tile B row base (1024..1984)
  const int tid = threadIdx.x;
  const int w = tid >> 6, lane = tid & 63;
  const int ww = w & 3;            // wave index within subtile group
  const int R = (w >> 2) ? RB : RA;  // this wave's subtile row base
  const int l16 = lane & 15, quad = lane >> 4;
  const int qrow16 = ww * 16 + l16;  // this lane's q-row within the 64-row subtile

  int idxR[4];                     // bpermute byte-idx: same-quad lane with l16 = quad*4+r
#pragma unroll
  for (int r = 0; r < 4; ++r) idxR[r] = ((lane & 48) | (quad * 4 + r)) << 2;

  // Q fragment for this wave's subtile (B-operand: col = q = l16)
  short8 qf[4];
  {
    const float* qp = Q + ((size_t)(h * SEQ + R + ww * 16 + l16)) * HD + quad * 8;
#pragma unroll
    for (int c = 0; c < 4; ++c) {
      f32x4 a = *(const f32x4*)(qp + c * 32);
      f32x4 bb = *(const f32x4*)(qp + c * 32 + 4);
      union { u32 u[4]; short8 v; } t;
      t.u[0] = cvtpk_bf16(a[0], a[1]);
      t.u[1] = cvtpk_bf16(a[2], a[3]);
      t.u[2] = cvtpk_bf16(bb[0], bb[1]);
      t.u[3] = cvtpk_bf16(bb[2], bb[3]);
      qf[c] = t.v;
    }
  }

  f32x4 o[8];
#pragma unroll
  for (int i = 0; i < 8; ++i) o[i] = (f32x4){0.f, 0.f, 0.f, 0.f};
  float mrow = NEGS, lrow = 0.f;

  // staging thread mapping (512 threads) + prefetch registers
  const int krow = tid >> 3, kqo = (tid & 7) * 16;   // K: 64 rows x 256B, 8 thr/row
  // token->LDS-row bit shuffle: x = [t5 t2 | t4 t3 | t1 t0]
  const int krp = (krow & 35) | (((krow >> 2) & 1) << 4) |
                  (((krow >> 4) & 1) << 3) | (((krow >> 3) & 1) << 2);
  // V^T: 128 rows x 64 u16, 4 thr/row; thread covers {vco, vco+32}, vco in {0,8,16,24}
  const int vd = tid >> 2, vco = (tid & 3) * 8;
  const u16* kbase = krec + ((size_t)h * SEQ + krow) * HD + kqo;
  const u16* vbase = vrecT + (size_t)h * 32 * 8192 + vd * 64 + vco;
  short8 kr[2], vr, vr2;
  kr[0] = *(const short8*)(kbase);
  kr[1] = *(const short8*)(kbase + 8);
  vr = *(const short8*)(vbase);
  vr2 = *(const short8*)(vbase + 32);

  const int ktiles = (RB >> 6) + 1;   // 17..32
  for (int kt = 0; kt < ktiles; ++kt) {
    const int kb = kt << 6;
    __syncthreads();                  // previous compute done with LDS
    *(short8*)(&ks[krp][kqo]) = kr[0];
    *(short8*)(&ks[krp][kqo + 8]) = kr[1];
    *(short8*)(&vt[vd][vco]) = vr;
    *(short8*)(&vt[vd][vco + 32]) = vr2;
    __syncthreads();
    if (kt + 1 < ktiles) {            // prefetch next tile under this tile's compute
      const u16* kp = kbase + (size_t)(kt + 1) * 64 * HD;
      const u16* vp = vbase + (size_t)(kt + 1) * 8192;
      kr[0] = *(const short8*)(kp);
      kr[1] = *(const short8*)(kp + 8);
      vr = *(const short8*)(vp);
      vr2 = *(const short8*)(vp + 32);
    }
    if (kb <= R) {
      // S^T = K Q^T: A = K frags from LDS, B = Q regs
      f32x4 s[4];
      __builtin_amdgcn_s_setprio(1);
#pragma unroll
      for (int ni = 0; ni < 4; ++ni) {
        f32x4 acc = (f32x4){0.f, 0.f, 0.f, 0.f};
#pragma unroll
        for (int c = 0; c < 4; ++c) {
          short8 kf = *(const short8*)(&ks[ni * 16 + l16][c * 32 + quad * 8]);
          acc = __builtin_amdgcn_mfma_f32_16x16x32_bf16(kf, qf[c], acc, 0, 0, 0);
        }
        s[ni] = acc;
      }
      __builtin_amdgcn_s_setprio(0);

      // softmax with defer-max; token of s[ni][r] = (ni>>1)*32 + quad*8 + (ni&1)*4 + r
      const bool diag = (kb == R);
#pragma unroll
      for (int ni = 0; ni < 4; ++ni)
#pragma unroll
        for (int r = 0; r < 4; ++r) {
          float sv = s[ni][r] * SC_QK;
          const int tokl = ((ni >> 1) << 5) | (quad << 3) | ((ni & 1) << 2) | r;
          if (diag && tokl > qrow16) sv = NEGS;
          s[ni][r] = sv;
        }
      float m01 = fmaxf(fmaxf(fmaxf(s[0][0], s[0][1]), fmaxf(s[0][2], s[0][3])),
                        fmaxf(fmaxf(s[1][0], s[1][1]), fmaxf(s[1][2], s[1][3])));
      float m23 = fmaxf(fmaxf(fmaxf(s[2][0], s[2][1]), fmaxf(s[2][2], s[2][3])),
                        fmaxf(fmaxf(s[3][0], s[3][1]), fmaxf(s[3][2], s[3][3])));
      float mx = fmaxf(m01, m23);
      mx = fmaxf(mx, __shfl_xor(mx, 16));
      mx = fmaxf(mx, __shfl_xor(mx, 32));
      const bool skip = (__ballot(mx <= mrow + 8.0f) == ~0ull);
      float al = 1.0f;
      if (!skip) {
        const float mnew = fmaxf(mrow, mx);
        al = exp2f(mrow - mnew);
        mrow = mnew;
      }
      float sum = 0.f;
#pragma unroll
      for (int ni = 0; ni < 4; ++ni)
#pragma unroll
        for (int r = 0; r < 4; ++r) {
          const float p = exp2f(s[ni][r] - mrow);
          s[ni][r] = p;
          sum += p;
        }
      sum += __shfl_xor(sum, 16);
      sum += __shfl_xor(sum, 32);
      lrow = skip ? (lrow + sum) : (lrow * al + sum);
      // pack P to bf16 pairs: pk[4*kc + {0..3}] = A-frag dwords for PV k-chunk kc
      u32 pk[8];
#pragma unroll
      for (int ni = 0; ni < 4; ++ni) {
        pk[ni * 2] = cvtpk_bf16(s[ni][0], s[ni][1]);
        pk[ni * 2 + 1] = cvtpk_bf16(s[ni][2], s[ni][3]);
      }
      if (!skip) {
        f32x4 av;   // alpha redistributed to output-row layout
#pragma unroll
        for (int r = 0; r < 4; ++r) av[r] = bperm_f(idxR[r], al);
#pragma unroll
        for (int i = 0; i < 8; ++i) o[i] *= av;
      }

      // O += P V  (P A-frags are lane-local registers; V frags from LDS)
      __builtin_amdgcn_s_setprio(1);
#pragma unroll
      for (int kc = 0; kc < 2; ++kc) {
        union { u32 u[4]; short8 v; } au;
#pragma unroll
        for (int t = 0; t < 4; ++t) au.u[t] = pk[kc * 4 + t];
        const short8 af = au.v;
#pragma unroll
        for (int ds = 0; ds < 8; ++ds) {
          short8 vf = *(const short8*)(&vt[ds * 16 + l16][kc * 32 + quad * 8]);
          o[ds] = __builtin_amdgcn_mfma_f32_16x16x32_bf16(af, vf, o[ds], 0, 0, 0);
        }
      }
      __builtin_amdgcn_s_setprio(0);
    }
  }

  // epilogue
  {
    float linv[4];
#pragma unroll
    for (int r = 0; r < 4; ++r) linv[r] = 1.0f / bperm_f(idxR[r], lrow);
#pragma unroll
    for (int r = 0; r < 4; ++r) {
      const int qr = R + ww * 16 + quad * 4 + r;
      float* op = Out + ((size_t)(h * SEQ + qr)) * HD + l16;
#pragma unroll
      for (int ds = 0; ds < 8; ++ds) op[ds * 16] = o[ds][r] * linv[r];
    }
  }
}

// ---------------- fallback flash (round-3/4 passing version, inline dequant) --------
__global__ __launch_bounds__(256, 2) void flash_fb(const float* __restrict__ Q,
                                                   const float* __restrict__ K,
                                                   const float* __restrict__ V,
                                                   const u32* __restrict__ ctrl,
                                                   const float* __restrict__ kscale,
                                                   const float* __restrict__ vscale,
                                                   float* __restrict__ Out) {
  __shared__ u16 ks[64][136];
  __shared__ u16 vt[128][72];
  __shared__ u16 pl[4][16][72];
  const int blk = blockIdx.x;
  const int h = blk >> 5;
  const int qt = 31 - (blk & 31);
  const int qb = qt << 6;
  const int tid = threadIdx.x;
  const int w = tid >> 6, lane = tid & 63;
  const int l16 = lane & 15, quad = lane >> 4;
  const float SM_SCALE = 0.08838834764831843f;
  const float NEG = -30000.0f;
  const u32 tK = ctrl[0];
  const u64 KrK = (((u64)ctrl[2]) << 32) | ctrl[3];
  const u32 tV = ctrl[8];
  const u64 KrV = (((u64)ctrl[10]) << 32) | ctrl[11];
  const int cch = (tid & 15) * 8;
  float ksc[8], vsc[8];
#pragma unroll
  for (int j = 0; j < 8; ++j) {
    ksc[j] = kscale[h * HD + cch + j];
    vsc[j] = vscale[h * HD + cch + j];
  }
  short8 qf[4];
  {
    const float* qp = Q + ((size_t)(h * SEQ + qb + w * 16 + l16)) * HD + quad * 8;
#pragma unroll
    for (int c = 0; c < 4; ++c) {
      f32x4 a = *(const f32x4*)(qp + c * 32);
      f32x4 b = *(const f32x4*)(qp + c * 32 + 4);
#pragma unroll
      for (int j = 0; j < 4; ++j) {
        qf[c][j] = (short)f2bf(a[j]);
        qf[c][4 + j] = (short)f2bf(b[j]);
      }
    }
  }
  f32x4 o[8];
#pragma unroll
  for (int i = 0; i < 8; ++i) o[i] = (f32x4){0.f, 0.f, 0.f, 0.f};
  float mrow[4], lrow[4];
#pragma unroll
  for (int r = 0; r < 4; ++r) { mrow[r] = NEG; lrow[r] = 0.f; }
  const int ktiles = qt + 1;
  for (int kt = 0; kt < ktiles; ++kt) {
    const int kb = kt << 6;
    __syncthreads();
    {
      const int r0 = tid >> 4;
      const float* kp = K + (size_t)(h * SEQ + kb) * HD;
#pragma unroll
      for (int i = 0; i < 4; ++i) {
        const int row = r0 + i * 16;
        f32x4 x0 = *(const f32x4*)(kp + (size_t)row * HD + cch);
        f32x4 x1 = *(const f32x4*)(kp + (size_t)row * HD + cch + 4);
        const u32 bidx = ((u32)(h * SEQ + kb + row) << 7) + (u32)cch;
        short8 yv;
#pragma unroll
        for (int j = 0; j < 4; ++j) {
          yv[j]     = (short)f2bf(dqf(x0[j], tK, KrK, bidx + j,     false, ksc[j]));
          yv[4 + j] = (short)f2bf(dqf(x1[j], tK, KrK, bidx + 4 + j, false, ksc[4 + j]));
        }
        *(short8*)(&ks[row][cch]) = yv;
      }
    }
    {
      const float* vp = V + (size_t)(h * SEQ + kb) * HD;
#pragma unroll
      for (int i = 0; i < 4; ++i) {
        const int tchunk = tid + i * 256;
        const int s = tchunk >> 4;
        const int tok = kb + s;
        const bool sink = tok < 4;
        f32x4 x0 = *(const f32x4*)(vp + (size_t)s * HD + cch);
        f32x4 x1 = *(const f32x4*)(vp + (size_t)s * HD + cch + 4);
        const u32 bidx = ((u32)(h * SEQ + tok) << 7) + (u32)cch;
#pragma unroll
        for (int j = 0; j < 4; ++j) {
          vt[cch + j][s]     = f2bf(dqf(x0[j], tV, KrV, bidx + j,     sink, vsc[j]));
          vt[cch + 4 + j][s] = f2bf(dqf(x1[j], tV, KrV, bidx + 4 + j, sink, vsc[4 + j]));
        }
      }
    }
    __syncthreads();
    f32x4 sa[4];
#pragma unroll
    for (int ni = 0; ni < 4; ++ni) {
      f32x4 acc = (f32x4){0.f, 0.f, 0.f, 0.f};
#pragma unroll
      for (int c = 0; c < 4; ++c) {
        short8 kf = *(const short8*)(&ks[ni * 16 + l16][c * 32 + quad * 8]);
        acc = __builtin_amdgcn_mfma_f32_16x16x32_bf16(qf[c], kf, acc, 0, 0, 0);
      }
      sa[ni] = acc;
    }
    const bool diag = (kb == qb);
#pragma unroll
    for (int ni = 0; ni < 4; ++ni)
#pragma unroll
      for (int r = 0; r < 4; ++r) {
        float sv = sa[ni][r] * SM_SCALE;
        if (diag) {
          const int qr = w * 16 + quad * 4 + r;
          const int kc = ni * 16 + l16;
          if (kc > qr) sv = NEG;
        }
        sa[ni][r] = sv;
      }
    float alpha[4];
#pragma unroll
    for (int r = 0; r < 4; ++r) {
      float mx = fmaxf(fmaxf(sa[0][r], sa[1][r]), fmaxf(sa[2][r], sa[3][r]));
      mx = fmaxf(mx, __shfl_xor(mx, 1));
      mx = fmaxf(mx, __shfl_xor(mx, 2));
      mx = fmaxf(mx, __shfl_xor(mx, 4));
      mx = fmaxf(mx, __shfl_xor(mx, 8));
      const float mn = fmaxf(mrow[r], mx);
      alpha[r] = __expf(mrow[r] - mn);
      mrow[r] = mn;
      float sum = 0.f;
#pragma unroll
      for (int ni = 0; ni < 4; ++ni) {
        const float p = __expf(sa[ni][r] - mn);
        sa[ni][r] = p;
        sum += p;
      }
      sum += __shfl_xor(sum, 1);
      sum += __shfl_xor(sum, 2);
      sum += __shfl_xor(sum, 4);
      sum += __shfl_xor(sum, 8);
      lrow[r] = lrow[r] * alpha[r] + sum;
    }
#pragma unroll
    for (int ni = 0; ni < 4; ++ni)
#pragma unroll
      for (int r = 0; r < 4; ++r)
        pl[w][quad * 4 + r][ni * 16 + l16] = f2bf(sa[ni][r]);
    __syncthreads();
#pragma unroll
    for (int i = 0; i < 8; ++i)
#pragma unroll
      for (int r = 0; r < 4; ++r) o[i][r] *= alpha[r];
#pragma unroll
    for (int kc = 0; kc < 2; ++kc) {
      short8 af = *(const short8*)(&pl[w][l16][kc * 32 + quad * 8]);
#pragma unroll
      for (int ds = 0; ds < 8; ++ds) {
        short8 vf = *(const short8*)(&vt[ds * 16 + l16][kc * 32 + quad * 8]);
        o[ds] = __builtin_amdgcn_mfma_f32_16x16x32_bf16(af, vf, o[ds], 0, 0, 0);
      }
    }
  }
#pragma unroll
  for (int r = 0; r < 4; ++r) {
    const float inv = 1.0f / lrow[r];
    const int qr = qb + w * 16 + quad * 4 + r;
    float* op = Out + ((size_t)(h * SEQ + qr)) * HD + l16;
#pragma unroll
    for (int ds = 0; ds < 8; ++ds) op[ds * 16] = o[ds][r] * inv;
  }
}

// ---------------- launcher ----------------
extern "C" void kernel_launch(void* const* d_in, const int* in_sizes, int n_in,
                              void* d_out, int out_size, void* d_ws, size_t ws_size,
                              hipStream_t stream) {
  const float* q = (const float*)d_in[0];
  const float* k = (const float*)d_in[1];
  const float* v = (const float*)d_in[2];
  float* out = (float*)d_out;
  char* ws = (char*)d_ws;

  u32* ctrl    = (u32*)ws;                               // 256 B
  u32* histK   = (u32*)(ws + 256);                       // 128 KB
  u32* histV   = (u32*)(ws + 256 + 131072);              // 128 KB
  u32* kmax    = (u32*)(ws + 262400);                    // 16 KB
  u32* vmax    = (u32*)(ws + 278784);                    // 16 KB
  const size_t ZERO_BYTES = 295168;                      // ctrl+hists+maxes
  float* kscale = (float*)(ws + 295168);                 // 16 KB
  float* vscale = (float*)(ws + 311552);                 // 16 KB
  u32* caK = (u32*)(ws + 327936);                        // 4x32 KB
  u32* ciK = caK + CAND_CAP;
  u32* caV = ciK + CAND_CAP;
  u32* ciV = caV + CAND_CAP;
  u16* krec  = (u16*)(ws + 458752);                      // 16 MB
  u16* vrecT = (u16*)(ws + 458752 + 16777216);           // 16 MB
  const size_t NEED = 458752 + 2ull * 16777216;

  hipMemsetAsync(ws, 0, ZERO_BYTES, stream);
  hist_kernel<<<512, 512, 0, stream>>>(k, v, histK, histV);
  thresh_kernel<<<2, 256, 0, stream>>>(histK, histV, ctrl);
  candmax_kernel<<<dim3(256, 2), 512, 0, stream>>>(k, v, ctrl, caK, ciK, caV, ciV, kmax, vmax);
  ksel_kernel<<<dim3(32, 2), 256, 0, stream>>>(ctrl, caK, ciK, caV, ciV);
  maxfix_scale_kernel<<<2, 256, 0, stream>>>(ctrl, caK, ciK, caV, ciV, kmax, vmax, kscale, vscale);
  if (ws_size >= NEED) {
    recon_kv_kernel<<<3072, 256, 0, stream>>>(k, v, ctrl, kscale, vscale, krec, vrecT);
    flash_pre<<<512, 512, 0, stream>>>(q, krec, vrecT, out);
  } else {
    flash_fb<<<32 * 32, 256, 0, stream>>>(q, k, v, ctrl, kscale, vscale, out);
  }
}